// Round 1
// baseline (14031.815 us; speedup 1.0000x reference)
//
#include <hip/hip_runtime.h>
#include <math.h>

#define PI_F 3.14159265358979323846f

__device__ __forceinline__ float siluf(float x){ return x / (1.f + expf(-x)); }
__device__ __forceinline__ float softplusf(float x){ return fmaxf(x,0.f) + log1pf(expf(-fabsf(x))); }

// ---------------- DFT band filtering ----------------
// x (2,128,128) -> T[b,y,v] = sum_x x[b,y,x] e^{-2pi i v x/128}
__global__ void k_dft_rows(const float* __restrict__ x, float* __restrict__ Tre, float* __restrict__ Tim){
  int v = threadIdx.x; int y = blockIdx.x; int b = blockIdx.y;
  __shared__ float cs[128], sn[128];
  float ang = -2.f*PI_F*(float)v/128.f;
  cs[v]=cosf(ang); sn[v]=sinf(ang);
  __syncthreads();
  const float* row = x + (b*128+y)*128;
  float re=0.f, im=0.f;
  for(int n=0;n<128;n++){ float xv=row[n]; int ph=(v*n)&127; re=fmaf(xv,cs[ph],re); im=fmaf(xv,sn[ph],im); }
  int o=(b*128+y)*128+v; Tre[o]=re; Tim[o]=im;
}
// F[b,u,v] = sum_y T[b,y,v] e^{-2pi i u y/128}
__global__ void k_dft_cols(const float* __restrict__ Tre, const float* __restrict__ Tim,
                           float* __restrict__ Fre, float* __restrict__ Fim){
  int v=threadIdx.x; int u=blockIdx.x; int b=blockIdx.y;
  __shared__ float cs[128], sn[128];
  float ang=-2.f*PI_F*(float)v/128.f; cs[v]=cosf(ang); sn[v]=sinf(ang);
  __syncthreads();
  float re=0.f,im=0.f;
  for(int y=0;y<128;y++){
    int ph=(u*y)&127; float c=cs[ph], s=sn[ph];
    int o=(b*128+y)*128+v;
    float tr=Tre[o], ti=Tim[o];
    re += tr*c - ti*s; im += tr*s + ti*c;
  }
  int o=(b*128+u)*128+v; Fre[o]=re; Fim[o]=im;
}
// G[b,m,y,v] = (1/128) sum_u F[b,u,v]*mask[m,u,v]*e^{+2pi i u y/128}
__global__ void k_idft_cols(const float* __restrict__ Fre,const float* __restrict__ Fim,
                            const float* __restrict__ mask, float* __restrict__ Gre,float* __restrict__ Gim){
  int v=threadIdx.x; int y=blockIdx.x; int m=blockIdx.y; int b=blockIdx.z;
  __shared__ float cs[128], sn[128];
  float ang=-2.f*PI_F*(float)v/128.f; cs[v]=cosf(ang); sn[v]=sinf(ang);
  __syncthreads();
  float re=0.f,im=0.f;
  for(int u=0;u<128;u++){
    int ph=(u*y)&127; float c=cs[ph], s=sn[ph];   // e^{+i th} = c - i*s  (sn holds sin(-th))
    float w = mask[(m*128+u)*128+v];
    int o=(b*128+u)*128+v;
    float fr=Fre[o]*w, fi=Fim[o]*w;
    re += fr*c + fi*s;
    im += fi*c - fr*s;
  }
  int o=((b*3+m)*128+y)*128+v;
  Gre[o]=re*(1.f/128.f); Gim[o]=im*(1.f/128.f);
}
// x_freq[b,m,y,x] = Re{ (1/128) sum_v G[b,m,y,v] e^{+2pi i v x/128} }
__global__ void k_idft_rows(const float* __restrict__ Gre,const float* __restrict__ Gim, float* __restrict__ xf){
  int xc=threadIdx.x; int y=blockIdx.x; int m=blockIdx.y; int b=blockIdx.z;
  __shared__ float cs[128], sn[128];
  float ang=-2.f*PI_F*(float)xc/128.f; cs[xc]=cosf(ang); sn[xc]=sinf(ang);
  __syncthreads();
  float re=0.f;
  const float* gr=Gre+((b*3+m)*128+y)*128;
  const float* gi=Gim+((b*3+m)*128+y)*128;
  for(int v=0;v<128;v++){
    int ph=(v*xc)&127;
    re += gr[v]*cs[ph] + gi[v]*sn[ph];
  }
  xf[((b*3+m)*128+y)*128+xc] = re*(1.f/128.f);
}

// ---------------- conv 3x3 (pad 1) + bias + optional relu; optional concat (in1:C1, in2:C2) ----------------
__global__ void k_conv3x3(const float* __restrict__ in1, int C1, const float* __restrict__ in2, int C2,
                          const float* __restrict__ w, const float* __restrict__ bias, float* __restrict__ out,
                          int Co, int H, int W, int relu){
  int hw = blockIdx.x*blockDim.x + threadIdx.x;
  if (hw >= H*W) return;
  int co = blockIdx.y; int b = blockIdx.z;
  int y = hw / W, x = hw % W;
  int Ci = C1 + C2;
  float acc = bias[co];
  const float* wp = w + (size_t)co*Ci*9;
  for (int ci=0; ci<Ci; ci++){
    const float* src = (ci < C1) ? (in1 + ((size_t)(b*C1 + ci))*H*W)
                                 : (in2 + ((size_t)(b*C2 + (ci-C1)))*H*W);
    const float* wc = wp + ci*9;
    #pragma unroll
    for (int ky=0;ky<3;ky++){
      int yy = y+ky-1; if (yy<0||yy>=H) continue;
      const float* r = src + yy*W;
      #pragma unroll
      for (int kx=0;kx<3;kx++){
        int xx=x+kx-1; if(xx<0||xx>=W) continue;
        acc = fmaf(r[xx], wc[ky*3+kx], acc);
      }
    }
  }
  if (relu) acc = fmaxf(acc, 0.f);
  out[(((size_t)b*Co+co)*H + y)*W + x] = acc;
}

__global__ void k_maxpool2(const float* __restrict__ in, float* __restrict__ out, int BC, int H, int W){
  int Ho=H/2, Wo=W/2;
  int idx = blockIdx.x*blockDim.x + threadIdx.x;
  if (idx >= BC*Ho*Wo) return;
  int xo = idx % Wo; int yo = (idx / Wo) % Ho; int c = idx / (Wo*Ho);
  const float* p = in + ((size_t)c*H + 2*yo)*W + 2*xo;
  out[idx] = fmaxf(fmaxf(p[0],p[1]), fmaxf(p[W],p[W+1]));
}

// ---------------- Mamba ----------------
__global__ void k_build_tok(const float* __restrict__ p4, const float* __restrict__ cls,
                            float* __restrict__ hidden, float* __restrict__ residual){
  int idx = blockIdx.x*blockDim.x+threadIdx.x;
  if (idx >= 2*65*512) return;
  int d = idx % 512; int l = (idx/512)%65; int b = idx/(512*65);
  float v = (l==0) ? cls[d] : p4[((size_t)b*512+d)*64 + (l-1)];
  hidden[idx]=v; residual[idx]=v;
}

// residual += hidden; hs = LN(residual)*nw + nb   (rows of 512, 256 threads/row)
__global__ void k_add_ln(float* __restrict__ residual, const float* __restrict__ hidden,
                         const float* __restrict__ nw, const float* __restrict__ nb, float* __restrict__ hs){
  int row = blockIdx.x;
  int t = threadIdx.x;
  __shared__ float red[256];
  size_t base = (size_t)row*512;
  float v0 = residual[base + t]       + hidden[base + t];
  float v1 = residual[base + 256 + t] + hidden[base + 256 + t];
  residual[base+t]=v0; residual[base+256+t]=v1;
  red[t]=v0+v1; __syncthreads();
  for(int o=128;o>0;o>>=1){ if(t<o) red[t]+=red[t+o]; __syncthreads(); }
  float mean = red[0]/512.f; __syncthreads();
  float d0=v0-mean, d1=v1-mean;
  red[t]=d0*d0+d1*d1; __syncthreads();
  for(int o=128;o>0;o>>=1){ if(t<o) red[t]+=red[t+o]; __syncthreads(); }
  float rstd = rsqrtf(red[0]/512.f + 1e-5f);
  hs[base+t]     = d0*rstd*nw[t]     + nb[t];
  hs[base+256+t] = d1*rstd*nw[256+t] + nb[256+t];
}

// C[M,N] = act(A[M,K](lda) * B[N,K]^T + bias)   act: 0 none, 1 softplus
#define GBM 32
#define GBN 32
#define GBK 32
__global__ void k_gemm(const float* __restrict__ A, int lda, const float* __restrict__ Bw,
                       const float* __restrict__ bias, float* __restrict__ C,
                       int M, int N, int K, int act){
  __shared__ float As[GBM][GBK+1];
  __shared__ float Bs[GBN][GBK+1];
  int bm = blockIdx.y*GBM, bn = blockIdx.x*GBN;
  int t = threadIdx.x;
  float acc[4] = {0.f,0.f,0.f,0.f};
  int tm = t>>3, tn = (t&7)*4;
  for (int k0=0;k0<K;k0+=GBK) {
    for (int i=t; i<GBM*GBK; i+=256) {
      int m = i>>5, k = i&31;
      As[m][k] = (bm+m<M && k0+k<K)? A[(size_t)(bm+m)*lda + k0+k] : 0.f;
    }
    for (int i=t;i<GBN*GBK;i+=256){
      int n=i>>5,k=i&31;
      Bs[n][k] = (bn+n<N && k0+k<K)? Bw[(size_t)(bn+n)*K + k0+k] : 0.f;
    }
    __syncthreads();
    #pragma unroll
    for (int k=0;k<GBK;k++){
      float a = As[tm][k];
      acc[0]=fmaf(a,Bs[tn+0][k],acc[0]);
      acc[1]=fmaf(a,Bs[tn+1][k],acc[1]);
      acc[2]=fmaf(a,Bs[tn+2][k],acc[2]);
      acc[3]=fmaf(a,Bs[tn+3][k],acc[3]);
    }
    __syncthreads();
  }
  int m = bm+tm;
  if (m<M){
    #pragma unroll
    for (int j=0;j<4;j++){
      int n = bn+tn+j;
      if(n<N){
        float v = acc[j] + (bias? bias[n]:0.f);
        if (act==1) v = softplusf(v);
        C[(size_t)m*N + n] = v;
      }
    }
  }
}

// depthwise causal conv1d (k=4, pad 3 left) + bias + silu.  xz (2,65,2048) -> xc (2,65,1024)
__global__ void k_conv1d_silu(const float* __restrict__ xz, const float* __restrict__ cw,
                              const float* __restrict__ cb, float* __restrict__ xc){
  int d = blockIdx.x*blockDim.x + threadIdx.x;
  int l = blockIdx.y, b = blockIdx.z;
  if (d>=1024) return;
  float acc = cb[d];
  #pragma unroll
  for(int k=0;k<4;k++){
    int lp = l-3+k;
    if (lp>=0) acc = fmaf(xz[((size_t)(b*65+lp))*2048 + d], cw[d*4+k], acc);
  }
  xc[((size_t)(b*65+l))*1024 + d] = siluf(acc);
}

// selective scan; one thread per (b,d); writes gated = (y + D*xc) * silu(z)
__global__ void k_scan(const float* __restrict__ dt, const float* __restrict__ xc,
                       const float* __restrict__ xdbl, const float* __restrict__ xz,
                       const float* __restrict__ Alog, const float* __restrict__ Dp,
                       float* __restrict__ gated){
  int tid = blockIdx.x*blockDim.x + threadIdx.x;
  if (tid >= 2048) return;
  int b = tid >> 10; int d = tid & 1023;
  float A[16], h[16];
  #pragma unroll
  for(int n=0;n<16;n++){ A[n] = -expf(Alog[d*16+n]); h[n]=0.f; }
  float Dv = Dp[d];
  for(int l=0;l<65;l++){
    size_t r = (size_t)(b*65+l);
    float dtv = dt[r*1024+d];
    float xcv = xc[r*1024+d];
    const float* xd = xdbl + r*64;
    float dtx = dtv*xcv;
    float y=0.f;
    #pragma unroll
    for(int n=0;n<16;n++){
      float dA = expf(dtv*A[n]);
      h[n] = fmaf(dA, h[n], dtx*xd[32+n]);
      y = fmaf(h[n], xd[48+n], y);
    }
    float zv = xz[r*2048 + 1024 + d];
    gated[r*1024+d] = (y + Dv*xcv) * siluf(zv);
  }
}

__global__ void k_xsp(const float* __restrict__ hidden, float* __restrict__ xsp){
  int idx = blockIdx.x*blockDim.x+threadIdx.x;
  if (idx>=2*512*64) return;
  int j = idx & 63; int c = (idx>>6)&511; int b = idx>>15;
  xsp[idx] = hidden[((size_t)(b*65 + 1 + j))*512 + c];
}

// transposed 2x2 stride-2 upsample: out[b,o,2i+p,2j+q] = sum_c in[b,c,i,j]*w[c,o,p,q] + bias[o]
__global__ void k_up2(const float* __restrict__ in, const float* __restrict__ w,
                      const float* __restrict__ bias, float* __restrict__ out,
                      int Ci, int Co, int Hi, int Wi){
  int Ho=2*Hi, Wo=2*Wi;
  int hw = blockIdx.x*blockDim.x + threadIdx.x;
  if (hw >= Ho*Wo) return;
  int o = blockIdx.y, b = blockIdx.z;
  int y=hw/Wo, x=hw%Wo;
  int i=y>>1, p=y&1, j=x>>1, q=x&1;
  float acc = bias[o];
  for(int c=0;c<Ci;c++){
    acc = fmaf(in[(((size_t)b*Ci+c)*Hi + i)*Wi + j], w[(((size_t)c*Co+o)*2 + p)*2 + q], acc);
  }
  out[(((size_t)b*Co+o)*Ho + y)*Wo + x] = acc;
}

__global__ void k_conv1x1(const float* __restrict__ in, const float* __restrict__ w,
                          const float* __restrict__ bias, float* __restrict__ out){
  int hw = blockIdx.x*blockDim.x+threadIdx.x; if (hw>=128*128) return;
  int o = blockIdx.y, b = blockIdx.z;
  float acc = bias[o];
  #pragma unroll
  for(int c=0;c<32;c++) acc = fmaf(in[((size_t)(b*32+c))*16384 + hw], w[o*32+c], acc);
  out[((size_t)(b*4+o))*16384 + hw] = acc;
}

// bilinear x16 (jax.image.resize semantics: half-pixel + edge renorm == clamped lerp)
__global__ void k_resize16(const float* __restrict__ in, float* __restrict__ out){
  size_t idx = (size_t)blockIdx.x*blockDim.x + threadIdx.x;
  if (idx >= (size_t)2*4*2048*2048) return;
  int x = idx & 2047; int y = (int)((idx>>11)&2047); int c = (int)(idx>>22);
  float sx = ((float)x+0.5f)*(1.f/16.f) - 0.5f;
  float sy = ((float)y+0.5f)*(1.f/16.f) - 0.5f;
  int x0 = (int)floorf(sx); float fx = sx-(float)x0;
  int y0 = (int)floorf(sy); float fy = sy-(float)y0;
  int x0c = max(x0,0), x1c = min(x0+1,127);
  int y0c = max(y0,0), y1c = min(y0+1,127);
  const float* p = in + (size_t)c*16384;
  float v00=p[y0c*128+x0c], v01=p[y0c*128+x1c], v10=p[y1c*128+x0c], v11=p[y1c*128+x1c];
  out[idx] = (1.f-fy)*((1.f-fx)*v00 + fx*v01) + fy*((1.f-fx)*v10 + fx*v11);
}

// ---------------- host ----------------
static inline void gemm_launch(hipStream_t s, const float* A, int lda, const float* Bw,
                               const float* bias, float* C, int M, int N, int K, int act){
  dim3 grid((N+GBN-1)/GBN, (M+GBM-1)/GBM);
  hipLaunchKernelGGL(k_gemm, grid, dim3(256), 0, s, A, lda, Bw, bias, C, M, N, K, act);
}

extern "C" void kernel_launch(void* const* d_in, const int* in_sizes, int n_in,
                              void* d_out, int out_size, void* d_ws, size_t ws_size,
                              hipStream_t stream) {
  const float* x        = (const float*)d_in[0];
  const float* masks    = (const float*)d_in[1];
  const float* ew1[4] = {(const float*)d_in[2],(const float*)d_in[6],(const float*)d_in[10],(const float*)d_in[14]};
  const float* eb1[4] = {(const float*)d_in[3],(const float*)d_in[7],(const float*)d_in[11],(const float*)d_in[15]};
  const float* ew2[4] = {(const float*)d_in[4],(const float*)d_in[8],(const float*)d_in[12],(const float*)d_in[16]};
  const float* eb2[4] = {(const float*)d_in[5],(const float*)d_in[9],(const float*)d_in[13],(const float*)d_in[17]};
  const float* cls      = (const float*)d_in[18];
  const float* norm_w   = (const float*)d_in[19];
  const float* norm_b   = (const float*)d_in[20];
  const float* in_proj  = (const float*)d_in[21];
  const float* conv1d_w = (const float*)d_in[22];
  const float* conv1d_b = (const float*)d_in[23];
  const float* x_proj   = (const float*)d_in[24];
  const float* dt_w     = (const float*)d_in[25];
  const float* dt_b     = (const float*)d_in[26];
  const float* A_log    = (const float*)d_in[27];
  const float* D_ssm    = (const float*)d_in[28];
  const float* out_proj = (const float*)d_in[29];
  const float* dup_w[4] = {(const float*)d_in[30],(const float*)d_in[36],(const float*)d_in[42],(const float*)d_in[48]}; // d4,d3,d2,d1
  const float* dup_b[4] = {(const float*)d_in[31],(const float*)d_in[37],(const float*)d_in[43],(const float*)d_in[49]};
  const float* dw1[4]   = {(const float*)d_in[32],(const float*)d_in[38],(const float*)d_in[44],(const float*)d_in[50]};
  const float* db1[4]   = {(const float*)d_in[33],(const float*)d_in[39],(const float*)d_in[45],(const float*)d_in[51]};
  const float* dw2[4]   = {(const float*)d_in[34],(const float*)d_in[40],(const float*)d_in[46],(const float*)d_in[52]};
  const float* db2[4]   = {(const float*)d_in[35],(const float*)d_in[41],(const float*)d_in[47],(const float*)d_in[53]};
  const float* final_w  = (const float*)d_in[54];
  const float* final_b  = (const float*)d_in[55];
  float* out = (float*)d_out;

  float* W = (float*)d_ws;
  size_t off = 0;
  auto alloc = [&](size_t n){ float* p = W + off; off += n; return p; };

  float* Tre = alloc(32768);  float* Tim = alloc(32768);
  float* Fre = alloc(32768);  float* Fim = alloc(32768);
  float* Gre = alloc(196608); float* Gim = alloc(196608);
  float* xfreq = alloc(98304);
  float* tmpA = alloc(2097152);          // conv intermediates (max: e1 stage)
  float* e1 = alloc(2097152);
  float* p1 = alloc(524288);
  float* e2 = alloc(1048576);
  float* p2 = alloc(262144);
  float* e3 = alloc(524288);
  float* p3 = alloc(131072);
  float* e4 = alloc(262144);
  float* p4 = alloc(65536);
  float* hidden   = alloc(66560);
  float* residual = alloc(66560);
  float* hs  = alloc(66560);
  float* xz  = alloc(266240);
  float* xc  = alloc(133120);
  float* xdbl= alloc(8320);
  float* dtb = alloc(133120);
  float* gated = alloc(133120);
  float* xsp = alloc(65536);
  float* tmpB = alloc(1048576);          // upsample outputs (max: d1 stage)
  float* d4 = alloc(131072);
  float* d3 = alloc(262144);
  float* d2 = alloc(524288);
  float* d1 = alloc(1048576);
  float* fin = alloc(131072);
  (void)ws_size; (void)n_in; (void)in_sizes; (void)out_size;

  // ---- frequency band split ----
  hipLaunchKernelGGL(k_dft_rows, dim3(128,2), dim3(128), 0, stream, x, Tre, Tim);
  hipLaunchKernelGGL(k_dft_cols, dim3(128,2), dim3(128), 0, stream, Tre, Tim, Fre, Fim);
  hipLaunchKernelGGL(k_idft_cols, dim3(128,3,2), dim3(128), 0, stream, Fre, Fim, masks, Gre, Gim);
  hipLaunchKernelGGL(k_idft_rows, dim3(128,3,2), dim3(128), 0, stream, Gre, Gim, xfreq);

  // ---- encoder ----
  auto conv = [&](const float* i1,int C1,const float* i2,int C2,const float* w,const float* b,
                  float* o,int Co,int H,int Wd,int relu){
    dim3 grid((H*Wd+255)/256, Co, 2);
    hipLaunchKernelGGL(k_conv3x3, grid, dim3(256), 0, stream, i1, C1, i2, C2, w, b, o, Co, H, Wd, relu);
  };
  conv(xfreq,3,  nullptr,0, ew1[0], eb1[0], tmpA, 64, 128,128, 1);
  conv(tmpA,64,  nullptr,0, ew2[0], eb2[0], e1,   64, 128,128, 1);
  hipLaunchKernelGGL(k_maxpool2, dim3((2*64*64*64+255)/256), dim3(256), 0, stream, e1, p1, 2*64, 128,128);
  conv(p1,64,    nullptr,0, ew1[1], eb1[1], tmpA, 128, 64,64, 1);
  conv(tmpA,128, nullptr,0, ew2[1], eb2[1], e2,   128, 64,64, 1);
  hipLaunchKernelGGL(k_maxpool2, dim3((2*128*32*32+255)/256), dim3(256), 0, stream, e2, p2, 2*128, 64,64);
  conv(p2,128,   nullptr,0, ew1[2], eb1[2], tmpA, 256, 32,32, 1);
  conv(tmpA,256, nullptr,0, ew2[2], eb2[2], e3,   256, 32,32, 1);
  hipLaunchKernelGGL(k_maxpool2, dim3((2*256*16*16+255)/256), dim3(256), 0, stream, e3, p3, 2*256, 32,32);
  conv(p3,256,   nullptr,0, ew1[3], eb1[3], tmpA, 512, 16,16, 1);
  conv(tmpA,512, nullptr,0, ew2[3], eb2[3], e4,   512, 16,16, 1);
  hipLaunchKernelGGL(k_maxpool2, dim3((2*512*8*8+255)/256), dim3(256), 0, stream, e4, p4, 2*512, 16,16);

  // ---- mamba stack ----
  hipLaunchKernelGGL(k_build_tok, dim3((2*65*512+255)/256), dim3(256), 0, stream, p4, cls, hidden, residual);
  for (int l=0;l<24;l++){
    const float* nw   = norm_w   + (size_t)l*512;
    const float* nb   = norm_b   + (size_t)l*512;
    const float* inW  = in_proj  + (size_t)l*2048*512;
    const float* cw   = conv1d_w + (size_t)l*1024*4;
    const float* cb   = conv1d_b + (size_t)l*1024;
    const float* xpW  = x_proj   + (size_t)l*64*1024;
    const float* dtW  = dt_w     + (size_t)l*1024*32;
    const float* dtB  = dt_b     + (size_t)l*1024;
    const float* Alg  = A_log    + (size_t)l*1024*16;
    const float* Dp   = D_ssm    + (size_t)l*1024;
    const float* outW = out_proj + (size_t)l*512*1024;

    hipLaunchKernelGGL(k_add_ln, dim3(130), dim3(256), 0, stream, residual, hidden, nw, nb, hs);
    gemm_launch(stream, hs, 512, inW, nullptr, xz, 130, 2048, 512, 0);
    hipLaunchKernelGGL(k_conv1d_silu, dim3(4,65,2), dim3(256), 0, stream, xz, cw, cb, xc);
    gemm_launch(stream, xc, 1024, xpW, nullptr, xdbl, 130, 64, 1024, 0);
    gemm_launch(stream, xdbl, 64, dtW, dtB, dtb, 130, 1024, 32, 1);
    hipLaunchKernelGGL(k_scan, dim3(8), dim3(256), 0, stream, dtb, xc, xdbl, xz, Alg, Dp, gated);
    gemm_launch(stream, gated, 1024, outW, nullptr, hidden, 130, 512, 1024, 0);
  }
  hipLaunchKernelGGL(k_xsp, dim3((2*512*64+255)/256), dim3(256), 0, stream, hidden, xsp);

  // ---- decoder ----
  auto up = [&](const float* in,const float* w,const float* b,float* o,int Ci,int Co,int Hi){
    dim3 grid((4*Hi*Hi+255)/256, Co, 2);
    hipLaunchKernelGGL(k_up2, grid, dim3(256), 0, stream, in, w, b, o, Ci, Co, Hi, Hi);
  };
  // d4: up(xsp 512->256 @8), concat e4(512)+u(256)=768 -> conv 256 @16
  up(xsp, dup_w[0], dup_b[0], tmpB, 512, 256, 8);
  conv(e4,512, tmpB,256, dw1[0], db1[0], tmpA, 256, 16,16, 1);
  conv(tmpA,256, nullptr,0, dw2[0], db2[0], d4, 256, 16,16, 1);
  // d3
  up(d4, dup_w[1], dup_b[1], tmpB, 256, 128, 16);
  conv(e3,256, tmpB,128, dw1[1], db1[1], tmpA, 128, 32,32, 1);
  conv(tmpA,128, nullptr,0, dw2[1], db2[1], d3, 128, 32,32, 1);
  // d2
  up(d3, dup_w[2], dup_b[2], tmpB, 128, 64, 32);
  conv(e2,128, tmpB,64, dw1[2], db1[2], tmpA, 64, 64,64, 1);
  conv(tmpA,64, nullptr,0, dw2[2], db2[2], d2, 64, 64,64, 1);
  // d1
  up(d2, dup_w[3], dup_b[3], tmpB, 64, 32, 64);
  conv(e1,64, tmpB,32, dw1[3], db1[3], tmpA, 32, 128,128, 1);
  conv(tmpA,32, nullptr,0, dw2[3], db2[3], d1, 32, 128,128, 1);

  // ---- head ----
  hipLaunchKernelGGL(k_conv1x1, dim3((16384+255)/256, 4, 2), dim3(256), 0, stream, d1, final_w, final_b, fin);
  hipLaunchKernelGGL(k_resize16, dim3((size_t)(2*4*2048*2048)/256), dim3(256), 0, stream, fin, out);
}

// Round 2
// 11637.024 us; speedup vs baseline: 1.2058x; 1.2058x over previous
//
#include <hip/hip_runtime.h>
#include <math.h>

#define PI_F 3.14159265358979323846f

__device__ __forceinline__ float siluf(float x){ return x / (1.f + expf(-x)); }
__device__ __forceinline__ float softplusf(float x){ return fmaxf(x,0.f) + log1pf(expf(-fabsf(x))); }

// ---------------- DFT band filtering ----------------
__global__ void k_dft_rows(const float* __restrict__ x, float* __restrict__ Tre, float* __restrict__ Tim){
  int v = threadIdx.x; int y = blockIdx.x; int b = blockIdx.y;
  __shared__ float cs[128], sn[128];
  float ang = -2.f*PI_F*(float)v/128.f;
  cs[v]=cosf(ang); sn[v]=sinf(ang);
  __syncthreads();
  const float* row = x + (b*128+y)*128;
  float re=0.f, im=0.f;
  for(int n=0;n<128;n++){ float xv=row[n]; int ph=(v*n)&127; re=fmaf(xv,cs[ph],re); im=fmaf(xv,sn[ph],im); }
  int o=(b*128+y)*128+v; Tre[o]=re; Tim[o]=im;
}
__global__ void k_dft_cols(const float* __restrict__ Tre, const float* __restrict__ Tim,
                           float* __restrict__ Fre, float* __restrict__ Fim){
  int v=threadIdx.x; int u=blockIdx.x; int b=blockIdx.y;
  __shared__ float cs[128], sn[128];
  float ang=-2.f*PI_F*(float)v/128.f; cs[v]=cosf(ang); sn[v]=sinf(ang);
  __syncthreads();
  float re=0.f,im=0.f;
  for(int y=0;y<128;y++){
    int ph=(u*y)&127; float c=cs[ph], s=sn[ph];
    int o=(b*128+y)*128+v;
    float tr=Tre[o], ti=Tim[o];
    re += tr*c - ti*s; im += tr*s + ti*c;
  }
  int o=(b*128+u)*128+v; Fre[o]=re; Fim[o]=im;
}
__global__ void k_idft_cols(const float* __restrict__ Fre,const float* __restrict__ Fim,
                            const float* __restrict__ mask, float* __restrict__ Gre,float* __restrict__ Gim){
  int v=threadIdx.x; int y=blockIdx.x; int m=blockIdx.y; int b=blockIdx.z;
  __shared__ float cs[128], sn[128];
  float ang=-2.f*PI_F*(float)v/128.f; cs[v]=cosf(ang); sn[v]=sinf(ang);
  __syncthreads();
  float re=0.f,im=0.f;
  for(int u=0;u<128;u++){
    int ph=(u*y)&127; float c=cs[ph], s=sn[ph];
    float w = mask[(m*128+u)*128+v];
    int o=(b*128+u)*128+v;
    float fr=Fre[o]*w, fi=Fim[o]*w;
    re += fr*c + fi*s;
    im += fi*c - fr*s;
  }
  int o=((b*3+m)*128+y)*128+v;
  Gre[o]=re*(1.f/128.f); Gim[o]=im*(1.f/128.f);
}
__global__ void k_idft_rows(const float* __restrict__ Gre,const float* __restrict__ Gim, float* __restrict__ xf){
  int xc=threadIdx.x; int y=blockIdx.x; int m=blockIdx.y; int b=blockIdx.z;
  __shared__ float cs[128], sn[128];
  float ang=-2.f*PI_F*(float)xc/128.f; cs[xc]=cosf(ang); sn[xc]=sinf(ang);
  __syncthreads();
  float re=0.f;
  const float* gr=Gre+((b*3+m)*128+y)*128;
  const float* gi=Gim+((b*3+m)*128+y)*128;
  for(int v=0;v<128;v++){
    int ph=(v*xc)&127;
    re += gr[v]*cs[ph] + gi[v]*sn[ph];
  }
  xf[((b*3+m)*128+y)*128+xc] = re*(1.f/128.f);
}

// ---------------- tiled conv3x3 ----------------
// Block: 256 thr = 4 waves. Each wave: 16x16 pixel tile, 2x2 per lane, NCO output
// channels per wave (wave w -> co group). Input halo tile (18x18, CK channels) in LDS.
#define CK 8
#define RS 20            // LDS row stride (floats), even for 8B alignment
template<int NCO>
__global__ __launch_bounds__(256) void k_conv3x3_t(
    const float* __restrict__ in1, int C1, const float* __restrict__ in2, int C2,
    const float* __restrict__ w, const float* __restrict__ bias, float* __restrict__ out,
    int Co, int H, int W, int tilesX, int relu){
  __shared__ __align__(16) float smIn[CK*18*RS];
  __shared__ __align__(16) float smW[4*NCO*CK*12];
  int Ci = C1 + C2;
  int b = blockIdx.z;
  int co_block = blockIdx.y * 4 * NCO;
  int tx = (blockIdx.x % tilesX) * 16;
  int ty = (blockIdx.x / tilesX) * 16;
  int tid = threadIdx.x;
  int w_ = tid >> 6, lane = tid & 63;
  int lx = (lane & 7) * 2, ly = (lane >> 3) * 2;

  float acc[NCO][4];
  #pragma unroll
  for (int n=0;n<NCO;n++){ acc[n][0]=0.f; acc[n][1]=0.f; acc[n][2]=0.f; acc[n][3]=0.f; }

  for (int ci0 = 0; ci0 < Ci; ci0 += CK) {
    // stage input halo tile: CK channels x 18x18
    for (int i = tid; i < CK*18*18; i += 256) {
      int c = i % 18; int r = (i/18) % 18; int cc = i / 324;
      int ci = ci0 + cc;
      int y = ty - 1 + r, x = tx - 1 + c;
      float v = 0.f;
      if (ci < Ci && y >= 0 && y < H && x >= 0 && x < W) {
        v = (ci < C1) ? in1[(((size_t)b*C1 + ci)*H + y)*W + x]
                      : in2[(((size_t)b*C2 + (ci-C1))*H + y)*W + x];
      }
      smIn[cc*(18*RS) + r*RS + c] = v;
    }
    // stage weights: 4 waves x NCO x CK x 9 (12-float slots)
    for (int i = tid; i < 4*NCO*CK*9; i += 256) {
      int k = i % 9; int t = i / 9;
      int cc = t % CK; t /= CK;
      int n = t % NCO; int wv = t / NCO;
      int ci = ci0 + cc;
      int co = co_block + wv*NCO + n;
      smW[((wv*NCO+n)*CK + cc)*12 + k] = (ci < Ci) ? w[((size_t)co*Ci + ci)*9 + k] : 0.f;
    }
    __syncthreads();
    #pragma unroll
    for (int cc = 0; cc < CK; cc++) {
      const float* base = &smIn[cc*(18*RS)];
      float p[4][4];
      #pragma unroll
      for (int r=0;r<4;r++){
        float2 a = *(const float2*)&base[(ly+r)*RS + lx];
        float2 bq= *(const float2*)&base[(ly+r)*RS + lx + 2];
        p[r][0]=a.x; p[r][1]=a.y; p[r][2]=bq.x; p[r][3]=bq.y;
      }
      #pragma unroll
      for (int n=0;n<NCO;n++){
        const float* wp = &smW[((w_*NCO+n)*CK + cc)*12];
        float4 w0 = *(const float4*)wp;
        float4 w1 = *(const float4*)(wp+4);
        float w8 = wp[8];
        float wk[9] = {w0.x,w0.y,w0.z,w0.w,w1.x,w1.y,w1.z,w1.w,w8};
        #pragma unroll
        for (int oy=0;oy<2;oy++)
          #pragma unroll
          for (int ox=0;ox<2;ox++){
            float s = acc[n][oy*2+ox];
            #pragma unroll
            for (int ky=0;ky<3;ky++)
              #pragma unroll
              for (int kx=0;kx<3;kx++)
                s = fmaf(p[oy+ky][ox+kx], wk[ky*3+kx], s);
            acc[n][oy*2+ox] = s;
          }
      }
    }
    __syncthreads();
  }
  // epilogue
  #pragma unroll
  for (int n=0;n<NCO;n++){
    int co = co_block + w_*NCO + n;
    float bv = bias[co];
    #pragma unroll
    for (int oy=0;oy<2;oy++)
      #pragma unroll
      for (int ox=0;ox<2;ox++){
        float v = acc[n][oy*2+ox] + bv;
        if (relu) v = fmaxf(v, 0.f);
        out[(((size_t)b*Co + co)*H + ty+ly+oy)*W + tx+lx+ox] = v;
      }
  }
}

__global__ void k_maxpool2(const float* __restrict__ in, float* __restrict__ out, int BC, int H, int W){
  int Ho=H/2, Wo=W/2;
  int idx = blockIdx.x*blockDim.x + threadIdx.x;
  if (idx >= BC*Ho*Wo) return;
  int xo = idx % Wo; int yo = (idx / Wo) % Ho; int c = idx / (Wo*Ho);
  const float* p = in + ((size_t)c*H + 2*yo)*W + 2*xo;
  out[idx] = fmaxf(fmaxf(p[0],p[1]), fmaxf(p[W],p[W+1]));
}

// ---------------- Mamba ----------------
__global__ void k_build_tok(const float* __restrict__ p4, const float* __restrict__ cls,
                            float* __restrict__ hidden, float* __restrict__ residual){
  int idx = blockIdx.x*blockDim.x+threadIdx.x;
  if (idx >= 2*65*512) return;
  int d = idx % 512; int l = (idx/512)%65; int b = idx/(512*65);
  float v = (l==0) ? cls[d] : p4[((size_t)b*512+d)*64 + (l-1)];
  hidden[idx]=v; residual[idx]=v;
}

__global__ void k_add_ln(float* __restrict__ residual, const float* __restrict__ hidden,
                         const float* __restrict__ nw, const float* __restrict__ nb, float* __restrict__ hs){
  int row = blockIdx.x;
  int t = threadIdx.x;
  __shared__ float red[256];
  size_t base = (size_t)row*512;
  float v0 = residual[base + t]       + hidden[base + t];
  float v1 = residual[base + 256 + t] + hidden[base + 256 + t];
  residual[base+t]=v0; residual[base+256+t]=v1;
  red[t]=v0+v1; __syncthreads();
  for(int o=128;o>0;o>>=1){ if(t<o) red[t]+=red[t+o]; __syncthreads(); }
  float mean = red[0]/512.f; __syncthreads();
  float d0=v0-mean, d1=v1-mean;
  red[t]=d0*d0+d1*d1; __syncthreads();
  for(int o=128;o>0;o>>=1){ if(t<o) red[t]+=red[t+o]; __syncthreads(); }
  float rstd = rsqrtf(red[0]/512.f + 1e-5f);
  hs[base+t]     = d0*rstd*nw[t]     + nb[t];
  hs[base+256+t] = d1*rstd*nw[256+t] + nb[256+t];
}

// C[M,N] = act(A[M,K](lda) * B[N,K]^T + bias)
#define GBM 32
#define GBN 32
#define GBK 32
__global__ void k_gemm(const float* __restrict__ A, int lda, const float* __restrict__ Bw,
                       const float* __restrict__ bias, float* __restrict__ C,
                       int M, int N, int K, int act){
  __shared__ float As[GBM][GBK+1];
  __shared__ float Bs[GBN][GBK+1];
  int bm = blockIdx.y*GBM, bn = blockIdx.x*GBN;
  int t = threadIdx.x;
  float acc[4] = {0.f,0.f,0.f,0.f};
  int tm = t>>3, tn = (t&7)*4;
  for (int k0=0;k0<K;k0+=GBK) {
    for (int i=t; i<GBM*GBK; i+=256) {
      int m = i>>5, k = i&31;
      As[m][k] = (bm+m<M && k0+k<K)? A[(size_t)(bm+m)*lda + k0+k] : 0.f;
    }
    for (int i=t;i<GBN*GBK;i+=256){
      int n=i>>5,k=i&31;
      Bs[n][k] = (bn+n<N && k0+k<K)? Bw[(size_t)(bn+n)*K + k0+k] : 0.f;
    }
    __syncthreads();
    #pragma unroll
    for (int k=0;k<GBK;k++){
      float a = As[tm][k];
      acc[0]=fmaf(a,Bs[tn+0][k],acc[0]);
      acc[1]=fmaf(a,Bs[tn+1][k],acc[1]);
      acc[2]=fmaf(a,Bs[tn+2][k],acc[2]);
      acc[3]=fmaf(a,Bs[tn+3][k],acc[3]);
    }
    __syncthreads();
  }
  int m = bm+tm;
  if (m<M){
    #pragma unroll
    for (int j=0;j<4;j++){
      int n = bn+tn+j;
      if(n<N){
        float v = acc[j] + (bias? bias[n]:0.f);
        if (act==1) v = softplusf(v);
        C[(size_t)m*N + n] = v;
      }
    }
  }
}

__global__ void k_conv1d_silu(const float* __restrict__ xz, const float* __restrict__ cw,
                              const float* __restrict__ cb, float* __restrict__ xc){
  int d = blockIdx.x*blockDim.x + threadIdx.x;
  int l = blockIdx.y, b = blockIdx.z;
  if (d>=1024) return;
  float acc = cb[d];
  #pragma unroll
  for(int k=0;k<4;k++){
    int lp = l-3+k;
    if (lp>=0) acc = fmaf(xz[((size_t)(b*65+lp))*2048 + d], cw[d*4+k], acc);
  }
  xc[((size_t)(b*65+l))*1024 + d] = siluf(acc);
}

// selective scan; lane per (b,d,n); shfl-reduce over n=16
__global__ void k_scan(const float* __restrict__ dt, const float* __restrict__ xc,
                       const float* __restrict__ xdbl, const float* __restrict__ xz,
                       const float* __restrict__ Alog, const float* __restrict__ Dp,
                       float* __restrict__ gated){
  int gid = blockIdx.x*blockDim.x + threadIdx.x;
  if (gid >= 2*1024*16) return;
  int n = gid & 15;
  int d = (gid >> 4) & 1023;
  int b = gid >> 14;
  float A = -expf(Alog[d*16+n]);
  float Dv = Dp[d];
  float h = 0.f;
  for (int l=0;l<65;l++){
    size_t r = (size_t)(b*65+l);
    float dtv = dt[r*1024+d];
    float xcv = xc[r*1024+d];
    float Bn = xdbl[r*64 + 32 + n];
    float Cn = xdbl[r*64 + 48 + n];
    h = fmaf(expf(dtv*A), h, dtv*xcv*Bn);
    float y = h*Cn;
    y += __shfl_xor(y, 1); y += __shfl_xor(y, 2);
    y += __shfl_xor(y, 4); y += __shfl_xor(y, 8);
    if (n==0){
      float zv = xz[r*2048 + 1024 + d];
      gated[r*1024+d] = (y + Dv*xcv) * siluf(zv);
    }
  }
}

__global__ void k_xsp(const float* __restrict__ hidden, float* __restrict__ xsp){
  int idx = blockIdx.x*blockDim.x+threadIdx.x;
  if (idx>=2*512*64) return;
  int j = idx & 63; int c = (idx>>6)&511; int b = idx>>15;
  xsp[idx] = hidden[((size_t)(b*65 + 1 + j))*512 + c];
}

__global__ void k_up2(const float* __restrict__ in, const float* __restrict__ w,
                      const float* __restrict__ bias, float* __restrict__ out,
                      int Ci, int Co, int Hi, int Wi){
  int Ho=2*Hi, Wo=2*Wi;
  int hw = blockIdx.x*blockDim.x + threadIdx.x;
  if (hw >= Ho*Wo) return;
  int o = blockIdx.y, b = blockIdx.z;
  int y=hw/Wo, x=hw%Wo;
  int i=y>>1, p=y&1, j=x>>1, q=x&1;
  float acc = bias[o];
  for(int c=0;c<Ci;c++){
    acc = fmaf(in[(((size_t)b*Ci+c)*Hi + i)*Wi + j], w[(((size_t)c*Co+o)*2 + p)*2 + q], acc);
  }
  out[(((size_t)b*Co+o)*Ho + y)*Wo + x] = acc;
}

__global__ void k_conv1x1(const float* __restrict__ in, const float* __restrict__ w,
                          const float* __restrict__ bias, float* __restrict__ out){
  int hw = blockIdx.x*blockDim.x+threadIdx.x; if (hw>=128*128) return;
  int o = blockIdx.y, b = blockIdx.z;
  float acc = bias[o];
  #pragma unroll
  for(int c=0;c<32;c++) acc = fmaf(in[((size_t)(b*32+c))*16384 + hw], w[o*32+c], acc);
  out[((size_t)(b*4+o))*16384 + hw] = acc;
}

__global__ void k_resize16(const float* __restrict__ in, float* __restrict__ out){
  size_t idx = (size_t)blockIdx.x*blockDim.x + threadIdx.x;
  if (idx >= (size_t)2*4*2048*2048) return;
  int x = idx & 2047; int y = (int)((idx>>11)&2047); int c = (int)(idx>>22);
  float sx = ((float)x+0.5f)*(1.f/16.f) - 0.5f;
  float sy = ((float)y+0.5f)*(1.f/16.f) - 0.5f;
  int x0 = (int)floorf(sx); float fx = sx-(float)x0;
  int y0 = (int)floorf(sy); float fy = sy-(float)y0;
  int x0c = max(x0,0), x1c = min(x0+1,127);
  int y0c = max(y0,0), y1c = min(y0+1,127);
  const float* p = in + (size_t)c*16384;
  float v00=p[y0c*128+x0c], v01=p[y0c*128+x1c], v10=p[y1c*128+x0c], v11=p[y1c*128+x1c];
  out[idx] = (1.f-fy)*((1.f-fx)*v00 + fx*v01) + fy*((1.f-fx)*v10 + fx*v11);
}

// ---------------- host ----------------
static inline void gemm_launch(hipStream_t s, const float* A, int lda, const float* Bw,
                               const float* bias, float* C, int M, int N, int K, int act){
  dim3 grid((N+GBN-1)/GBN, (M+GBM-1)/GBM);
  hipLaunchKernelGGL(k_gemm, grid, dim3(256), 0, s, A, lda, Bw, bias, C, M, N, K, act);
}

extern "C" void kernel_launch(void* const* d_in, const int* in_sizes, int n_in,
                              void* d_out, int out_size, void* d_ws, size_t ws_size,
                              hipStream_t stream) {
  const float* x        = (const float*)d_in[0];
  const float* masks    = (const float*)d_in[1];
  const float* ew1[4] = {(const float*)d_in[2],(const float*)d_in[6],(const float*)d_in[10],(const float*)d_in[14]};
  const float* eb1[4] = {(const float*)d_in[3],(const float*)d_in[7],(const float*)d_in[11],(const float*)d_in[15]};
  const float* ew2[4] = {(const float*)d_in[4],(const float*)d_in[8],(const float*)d_in[12],(const float*)d_in[16]};
  const float* eb2[4] = {(const float*)d_in[5],(const float*)d_in[9],(const float*)d_in[13],(const float*)d_in[17]};
  const float* cls      = (const float*)d_in[18];
  const float* norm_w   = (const float*)d_in[19];
  const float* norm_b   = (const float*)d_in[20];
  const float* in_proj  = (const float*)d_in[21];
  const float* conv1d_w = (const float*)d_in[22];
  const float* conv1d_b = (const float*)d_in[23];
  const float* x_proj   = (const float*)d_in[24];
  const float* dt_w     = (const float*)d_in[25];
  const float* dt_b     = (const float*)d_in[26];
  const float* A_log    = (const float*)d_in[27];
  const float* D_ssm    = (const float*)d_in[28];
  const float* out_proj = (const float*)d_in[29];
  const float* dup_w[4] = {(const float*)d_in[30],(const float*)d_in[36],(const float*)d_in[42],(const float*)d_in[48]};
  const float* dup_b[4] = {(const float*)d_in[31],(const float*)d_in[37],(const float*)d_in[43],(const float*)d_in[49]};
  const float* dw1[4]   = {(const float*)d_in[32],(const float*)d_in[38],(const float*)d_in[44],(const float*)d_in[50]};
  const float* db1[4]   = {(const float*)d_in[33],(const float*)d_in[39],(const float*)d_in[45],(const float*)d_in[51]};
  const float* dw2[4]   = {(const float*)d_in[34],(const float*)d_in[40],(const float*)d_in[46],(const float*)d_in[52]};
  const float* db2[4]   = {(const float*)d_in[35],(const float*)d_in[41],(const float*)d_in[47],(const float*)d_in[53]};
  const float* final_w  = (const float*)d_in[54];
  const float* final_b  = (const float*)d_in[55];
  float* out = (float*)d_out;

  float* W = (float*)d_ws;
  size_t off = 0;
  auto alloc = [&](size_t n){ float* p = W + off; off += n; return p; };

  float* Tre = alloc(32768);  float* Tim = alloc(32768);
  float* Fre = alloc(32768);  float* Fim = alloc(32768);
  float* Gre = alloc(196608); float* Gim = alloc(196608);
  float* xfreq = alloc(98304);
  float* tmpA = alloc(2097152);
  float* e1 = alloc(2097152);
  float* p1 = alloc(524288);
  float* e2 = alloc(1048576);
  float* p2 = alloc(262144);
  float* e3 = alloc(524288);
  float* p3 = alloc(131072);
  float* e4 = alloc(262144);
  float* p4 = alloc(65536);
  float* hidden   = alloc(66560);
  float* residual = alloc(66560);
  float* hs  = alloc(66560);
  float* xz  = alloc(266240);
  float* xc  = alloc(133120);
  float* xdbl= alloc(8320);
  float* dtb = alloc(133120);
  float* gated = alloc(133120);
  float* xsp = alloc(65536);
  float* tmpB = alloc(1048576);
  float* d4 = alloc(131072);
  float* d3 = alloc(262144);
  float* d2 = alloc(524288);
  float* d1 = alloc(1048576);
  float* fin = alloc(131072);
  (void)ws_size; (void)n_in; (void)in_sizes; (void)out_size;

  // ---- frequency band split ----
  hipLaunchKernelGGL(k_dft_rows, dim3(128,2), dim3(128), 0, stream, x, Tre, Tim);
  hipLaunchKernelGGL(k_dft_cols, dim3(128,2), dim3(128), 0, stream, Tre, Tim, Fre, Fim);
  hipLaunchKernelGGL(k_idft_cols, dim3(128,3,2), dim3(128), 0, stream, Fre, Fim, masks, Gre, Gim);
  hipLaunchKernelGGL(k_idft_rows, dim3(128,3,2), dim3(128), 0, stream, Gre, Gim, xfreq);

  // ---- tiled conv launcher ----
  auto conv = [&](const float* i1,int C1,const float* i2,int C2,const float* w,const float* b,
                  float* o,int Co,int H,int Wd,int relu){
    int tilesX = Wd/16;
    int tiles = (H/16)*tilesX;
    bool big = (Co%16==0) && (tiles*(Co/16)*2 >= 256);
    if (big){
      dim3 grid(tiles, Co/16, 2);
      hipLaunchKernelGGL((k_conv3x3_t<4>), grid, dim3(256), 0, stream, i1,C1,i2,C2,w,b,o,Co,H,Wd,tilesX,relu);
    } else {
      dim3 grid(tiles, Co/4, 2);
      hipLaunchKernelGGL((k_conv3x3_t<1>), grid, dim3(256), 0, stream, i1,C1,i2,C2,w,b,o,Co,H,Wd,tilesX,relu);
    }
  };

  // ---- encoder ----
  conv(xfreq,3,  nullptr,0, ew1[0], eb1[0], tmpA, 64, 128,128, 1);
  conv(tmpA,64,  nullptr,0, ew2[0], eb2[0], e1,   64, 128,128, 1);
  hipLaunchKernelGGL(k_maxpool2, dim3((2*64*64*64+255)/256), dim3(256), 0, stream, e1, p1, 2*64, 128,128);
  conv(p1,64,    nullptr,0, ew1[1], eb1[1], tmpA, 128, 64,64, 1);
  conv(tmpA,128, nullptr,0, ew2[1], eb2[1], e2,   128, 64,64, 1);
  hipLaunchKernelGGL(k_maxpool2, dim3((2*128*32*32+255)/256), dim3(256), 0, stream, e2, p2, 2*128, 64,64);
  conv(p2,128,   nullptr,0, ew1[2], eb1[2], tmpA, 256, 32,32, 1);
  conv(tmpA,256, nullptr,0, ew2[2], eb2[2], e3,   256, 32,32, 1);
  hipLaunchKernelGGL(k_maxpool2, dim3((2*256*16*16+255)/256), dim3(256), 0, stream, e3, p3, 2*256, 32,32);
  conv(p3,256,   nullptr,0, ew1[3], eb1[3], tmpA, 512, 16,16, 1);
  conv(tmpA,512, nullptr,0, ew2[3], eb2[3], e4,   512, 16,16, 1);
  hipLaunchKernelGGL(k_maxpool2, dim3((2*512*8*8+255)/256), dim3(256), 0, stream, e4, p4, 2*512, 16,16);

  // ---- mamba stack ----
  hipLaunchKernelGGL(k_build_tok, dim3((2*65*512+255)/256), dim3(256), 0, stream, p4, cls, hidden, residual);
  for (int l=0;l<24;l++){
    const float* nw   = norm_w   + (size_t)l*512;
    const float* nb   = norm_b   + (size_t)l*512;
    const float* inW  = in_proj  + (size_t)l*2048*512;
    const float* cw   = conv1d_w + (size_t)l*1024*4;
    const float* cb   = conv1d_b + (size_t)l*1024;
    const float* xpW  = x_proj   + (size_t)l*64*1024;
    const float* dtW  = dt_w     + (size_t)l*1024*32;
    const float* dtB  = dt_b     + (size_t)l*1024;
    const float* Alg  = A_log    + (size_t)l*1024*16;
    const float* Dp   = D_ssm    + (size_t)l*1024;
    const float* outW = out_proj + (size_t)l*512*1024;

    hipLaunchKernelGGL(k_add_ln, dim3(130), dim3(256), 0, stream, residual, hidden, nw, nb, hs);
    gemm_launch(stream, hs, 512, inW, nullptr, xz, 130, 2048, 512, 0);
    hipLaunchKernelGGL(k_conv1d_silu, dim3(4,65,2), dim3(256), 0, stream, xz, cw, cb, xc);
    gemm_launch(stream, xc, 1024, xpW, nullptr, xdbl, 130, 64, 1024, 0);
    gemm_launch(stream, xdbl, 64, dtW, dtB, dtb, 130, 1024, 32, 1);
    hipLaunchKernelGGL(k_scan, dim3(128), dim3(256), 0, stream, dtb, xc, xdbl, xz, Alg, Dp, gated);
    gemm_launch(stream, gated, 1024, outW, nullptr, hidden, 130, 512, 1024, 0);
  }
  hipLaunchKernelGGL(k_xsp, dim3((2*512*64+255)/256), dim3(256), 0, stream, hidden, xsp);

  // ---- decoder ----
  auto up = [&](const float* in,const float* w,const float* b,float* o,int Ci,int Co,int Hi){
    dim3 grid((4*Hi*Hi+255)/256, Co, 2);
    hipLaunchKernelGGL(k_up2, grid, dim3(256), 0, stream, in, w, b, o, Ci, Co, Hi, Hi);
  };
  up(xsp, dup_w[0], dup_b[0], tmpB, 512, 256, 8);
  conv(e4,512, tmpB,256, dw1[0], db1[0], tmpA, 256, 16,16, 1);
  conv(tmpA,256, nullptr,0, dw2[0], db2[0], d4, 256, 16,16, 1);
  up(d4, dup_w[1], dup_b[1], tmpB, 256, 128, 16);
  conv(e3,256, tmpB,128, dw1[1], db1[1], tmpA, 128, 32,32, 1);
  conv(tmpA,128, nullptr,0, dw2[1], db2[1], d3, 128, 32,32, 1);
  up(d3, dup_w[2], dup_b[2], tmpB, 128, 64, 32);
  conv(e2,128, tmpB,64, dw1[2], db1[2], tmpA, 64, 64,64, 1);
  conv(tmpA,64, nullptr,0, dw2[2], db2[2], d2, 64, 64,64, 1);
  up(d2, dup_w[3], dup_b[3], tmpB, 64, 32, 64);
  conv(e1,64, tmpB,32, dw1[3], db1[3], tmpA, 32, 128,128, 1);
  conv(tmpA,32, nullptr,0, dw2[3], db2[3], d1, 32, 128,128, 1);

  // ---- head ----
  hipLaunchKernelGGL(k_conv1x1, dim3((16384+255)/256, 4, 2), dim3(256), 0, stream, d1, final_w, final_b, fin);
  hipLaunchKernelGGL(k_resize16, dim3((size_t)(2*4*2048*2048)/256), dim3(256), 0, stream, fin, out);
}

// Round 4
// 9664.509 us; speedup vs baseline: 1.4519x; 1.2041x over previous
//
#include <hip/hip_runtime.h>
#include <math.h>

#define PI_F 3.14159265358979323846f
typedef _Float16 f16;
typedef __attribute__((ext_vector_type(8))) _Float16 f16x8;
typedef __attribute__((ext_vector_type(4))) float f32x4;

__device__ __forceinline__ float siluf(float x){ return x / (1.f + expf(-x)); }
__device__ __forceinline__ float softplusf(float x){ return fmaxf(x,0.f) + log1pf(expf(-fabsf(x))); }
__device__ __forceinline__ void f2hl(float v, f16& hi, f16& lo){
  hi = (f16)v;
  lo = (f16)(v - (float)hi);
}

// ---------------- DFT band filtering ----------------
__global__ void k_dft_rows(const float* __restrict__ x, float* __restrict__ Tre, float* __restrict__ Tim){
  int v = threadIdx.x; int y = blockIdx.x; int b = blockIdx.y;
  __shared__ float cs[128], sn[128];
  float ang = -2.f*PI_F*(float)v/128.f;
  cs[v]=cosf(ang); sn[v]=sinf(ang);
  __syncthreads();
  const float* row = x + (b*128+y)*128;
  float re=0.f, im=0.f;
  for(int n=0;n<128;n++){ float xv=row[n]; int ph=(v*n)&127; re=fmaf(xv,cs[ph],re); im=fmaf(xv,sn[ph],im); }
  int o=(b*128+y)*128+v; Tre[o]=re; Tim[o]=im;
}
__global__ void k_dft_cols(const float* __restrict__ Tre, const float* __restrict__ Tim,
                           float* __restrict__ Fre, float* __restrict__ Fim){
  int v=threadIdx.x; int u=blockIdx.x; int b=blockIdx.y;
  __shared__ float cs[128], sn[128];
  float ang=-2.f*PI_F*(float)v/128.f; cs[v]=cosf(ang); sn[v]=sinf(ang);
  __syncthreads();
  float re=0.f,im=0.f;
  for(int y=0;y<128;y++){
    int ph=(u*y)&127; float c=cs[ph], s=sn[ph];
    int o=(b*128+y)*128+v;
    float tr=Tre[o], ti=Tim[o];
    re += tr*c - ti*s; im += tr*s + ti*c;
  }
  int o=(b*128+u)*128+v; Fre[o]=re; Fim[o]=im;
}
__global__ void k_idft_cols(const float* __restrict__ Fre,const float* __restrict__ Fim,
                            const float* __restrict__ mask, float* __restrict__ Gre,float* __restrict__ Gim){
  int v=threadIdx.x; int y=blockIdx.x; int m=blockIdx.y; int b=blockIdx.z;
  __shared__ float cs[128], sn[128];
  float ang=-2.f*PI_F*(float)v/128.f; cs[v]=cosf(ang); sn[v]=sinf(ang);
  __syncthreads();
  float re=0.f,im=0.f;
  for(int u=0;u<128;u++){
    int ph=(u*y)&127; float c=cs[ph], s=sn[ph];
    float w = mask[(m*128+u)*128+v];
    int o=(b*128+u)*128+v;
    float fr=Fre[o]*w, fi=Fim[o]*w;
    re += fr*c + fi*s;
    im += fi*c - fr*s;
  }
  int o=((b*3+m)*128+y)*128+v;
  Gre[o]=re*(1.f/128.f); Gim[o]=im*(1.f/128.f);
}
__global__ void k_idft_rows(const float* __restrict__ Gre,const float* __restrict__ Gim, float* __restrict__ xf){
  int xc=threadIdx.x; int y=blockIdx.x; int m=blockIdx.y; int b=blockIdx.z;
  __shared__ float cs[128], sn[128];
  float ang=-2.f*PI_F*(float)xc/128.f; cs[xc]=cosf(ang); sn[xc]=sinf(ang);
  __syncthreads();
  float re=0.f;
  const float* gr=Gre+((b*3+m)*128+y)*128;
  const float* gi=Gim+((b*3+m)*128+y)*128;
  for(int v=0;v<128;v++){
    int ph=(v*xc)&127;
    re += gr[v]*cs[ph] + gi[v]*sn[ph];
  }
  xf[((b*3+m)*128+y)*128+xc] = re*(1.f/128.f);
}

// ---------------- f16 hi/lo prep kernels ----------------
// conv weight (N,K) fp32 -> (Np,Kp) f16 hi/lo zero-padded
__global__ void k_w2hl(const float* __restrict__ w, f16* __restrict__ dh, f16* __restrict__ dl,
                       int N, int K, int Kp){
  int k = blockIdx.x*256 + threadIdx.x;
  int n = blockIdx.y;
  if (k >= Kp) return;
  float v = (n < N && k < K) ? w[(size_t)n*K + k] : 0.f;
  f16 h,l; f2hl(v,h,l);
  dh[(size_t)n*Kp + k] = h; dl[(size_t)n*Kp + k] = l;
}
// up2 weight (Ci,Co,2,2) -> B[n=o*4+p*2+q][k=c]
__global__ void k_upw2hl(const float* __restrict__ w, f16* __restrict__ dh, f16* __restrict__ dl,
                         int Co, int K, int Kp){
  int k = blockIdx.x*256 + threadIdx.x;
  int n = blockIdx.y;
  if (k >= Kp) return;
  int o = n>>2, p=(n>>1)&1, q=n&1;
  float v = (k < K) ? w[(((size_t)k*Co + o)*2 + p)*2 + q] : 0.f;
  f16 h,l; f2hl(v,h,l);
  dh[(size_t)n*Kp + k] = h; dl[(size_t)n*Kp + k] = l;
}

// im2col: rows m0..m0+mc of M=B*H*W. k = ci*9 + (ky*3+kx) (ks3) or ci (ks1).
__global__ void k_im2col(const float* __restrict__ in1, int C1, const float* __restrict__ in2, int C2,
                         int H, int W, int wsh, int hwsh, int K, int Kp, int m0, int ks3,
                         f16* __restrict__ Ah, f16* __restrict__ Al){
  int k = blockIdx.x*256 + threadIdx.x;
  int lm = blockIdx.y;
  if (k >= Kp) return;
  float val = 0.f;
  if (k < K){
    int ci, dy, dx;
    if (ks3){ ci = k/9; int tt = k - ci*9; int r3 = tt/3; dy = r3 - 1; dx = tt - r3*3 - 1; }
    else { ci = k; dy = 0; dx = 0; }
    int m = m0 + lm;
    int b = m >> hwsh;
    int hw = m & ((1<<hwsh)-1);
    int y = (hw >> wsh) + dy;
    int x = (hw & (W-1)) + dx;
    if (y >= 0 && y < H && x >= 0 && x < W){
      val = (ci < C1) ? in1[(((size_t)b*C1 + ci)*H + y)*W + x]
                      : in2[(((size_t)b*C2 + (ci-C1))*H + y)*W + x];
    }
  }
  f16 h,l; f2hl(val,h,l);
  Ah[(size_t)lm*Kp + k] = h; Al[(size_t)lm*Kp + k] = l;
}

// ---------------- split-f16 MFMA GEMM ----------------
// out = W(Np,Kp) * P(mc,Kp)^T with W,P = hi+lo f16 pairs; 3 MFMAs per fragment pair.
// mode 0: out NCHW [(b*Co+co)*HW + hw], bias[co], optional relu
// mode 1: up2 scatter: co->(o,p,q), m->(b,i,j)
__global__ __launch_bounds__(256) void k_gemm_hl(
    const f16* __restrict__ Wh, const f16* __restrict__ Wl,
    const f16* __restrict__ Ph, const f16* __restrict__ Pl,
    const float* __restrict__ bias, float* __restrict__ out,
    int N, int Kp, int m0, int wsh, int hwsh, int Co, int relu, int mode)
{
  __shared__ f16 sWh[64*40];
  __shared__ f16 sWl[64*40];
  __shared__ f16 sPh[64*40];
  __shared__ f16 sPl[64*40];
  int bn = blockIdx.y*64;   // co tile
  int bm = blockIdx.x*64;   // pixel tile
  int t = threadIdx.x;
  int lane = t & 63, wv = t >> 6;
  int wr = wv >> 1, wc = wv & 1;
  f32x4 zz = {0.f,0.f,0.f,0.f};
  f32x4 acc[2][2];
  acc[0][0]=zz; acc[0][1]=zz; acc[1][0]=zz; acc[1][1]=zz;

  int srow = t>>2, scol = (t&3)*8;
  size_t offW = (size_t)(bn+srow)*Kp + scol;
  size_t offP = (size_t)(bm+srow)*Kp + scol;
  int ls = srow*40+scol;

  for (int k0 = 0; k0 < Kp; k0 += 32){
    *(f16x8*)&sWh[ls] = *(const f16x8*)(Wh + offW + k0);
    *(f16x8*)&sWl[ls] = *(const f16x8*)(Wl + offW + k0);
    *(f16x8*)&sPh[ls] = *(const f16x8*)(Ph + offP + k0);
    *(f16x8*)&sPl[ls] = *(const f16x8*)(Pl + offP + k0);
    __syncthreads();
    int rA = lane & 15, kc = (lane>>4)*8;
    f16x8 w0h = *(const f16x8*)&sWh[(wr*32 +    rA)*40 + kc];
    f16x8 w1h = *(const f16x8*)&sWh[(wr*32 + 16+rA)*40 + kc];
    f16x8 w0l = *(const f16x8*)&sWl[(wr*32 +    rA)*40 + kc];
    f16x8 w1l = *(const f16x8*)&sWl[(wr*32 + 16+rA)*40 + kc];
    f16x8 p0h = *(const f16x8*)&sPh[(wc*32 +    rA)*40 + kc];
    f16x8 p1h = *(const f16x8*)&sPh[(wc*32 + 16+rA)*40 + kc];
    f16x8 p0l = *(const f16x8*)&sPl[(wc*32 +    rA)*40 + kc];
    f16x8 p1l = *(const f16x8*)&sPl[(wc*32 + 16+rA)*40 + kc];
    acc[0][0] = __builtin_amdgcn_mfma_f32_16x16x32_f16(w0h, p0h, acc[0][0], 0,0,0);
    acc[0][0] = __builtin_amdgcn_mfma_f32_16x16x32_f16(w0h, p0l, acc[0][0], 0,0,0);
    acc[0][0] = __builtin_amdgcn_mfma_f32_16x16x32_f16(w0l, p0h, acc[0][0], 0,0,0);
    acc[0][1] = __builtin_amdgcn_mfma_f32_16x16x32_f16(w0h, p1h, acc[0][1], 0,0,0);
    acc[0][1] = __builtin_amdgcn_mfma_f32_16x16x32_f16(w0h, p1l, acc[0][1], 0,0,0);
    acc[0][1] = __builtin_amdgcn_mfma_f32_16x16x32_f16(w0l, p1h, acc[0][1], 0,0,0);
    acc[1][0] = __builtin_amdgcn_mfma_f32_16x16x32_f16(w1h, p0h, acc[1][0], 0,0,0);
    acc[1][0] = __builtin_amdgcn_mfma_f32_16x16x32_f16(w1h, p0l, acc[1][0], 0,0,0);
    acc[1][0] = __builtin_amdgcn_mfma_f32_16x16x32_f16(w1l, p0h, acc[1][0], 0,0,0);
    acc[1][1] = __builtin_amdgcn_mfma_f32_16x16x32_f16(w1h, p1h, acc[1][1], 0,0,0);
    acc[1][1] = __builtin_amdgcn_mfma_f32_16x16x32_f16(w1h, p1l, acc[1][1], 0,0,0);
    acc[1][1] = __builtin_amdgcn_mfma_f32_16x16x32_f16(w1l, p1h, acc[1][1], 0,0,0);
    __syncthreads();
  }

  int HW = 1<<hwsh;
  int Wi = 1<<wsh;
  int Hi = 1<<(hwsh-wsh);
  #pragma unroll
  for (int ri=0;ri<2;ri++)
  #pragma unroll
  for (int ci=0;ci<2;ci++)
  #pragma unroll
  for (int r=0;r<4;r++){
    int co = bn + wr*32 + ri*16 + (lane>>4)*4 + r;
    int pm = bm + wc*32 + ci*16 + (lane&15);
    if (co < N){
      float v = acc[ri][ci][r];
      int m = m0 + pm;
      int b = m >> hwsh;
      if (mode == 0){
        v += bias[co];
        if (relu) v = fmaxf(v, 0.f);
        int hw = m & (HW-1);
        out[((size_t)b*Co + co)*HW + hw] = v;
      } else {
        int o = co>>2, p=(co>>1)&1, q=co&1;
        v += bias[o];
        int ij = m & (HW-1);
        int i = ij >> wsh, j = ij & (Wi-1);
        out[(((size_t)b*Co + o)*(2*Hi) + 2*i+p)*(2*Wi) + 2*j+q] = v;
      }
    }
  }
}

__global__ void k_maxpool2(const float* __restrict__ in, float* __restrict__ out, int BC, int H, int W){
  int Ho=H/2, Wo=W/2;
  int idx = blockIdx.x*blockDim.x + threadIdx.x;
  if (idx >= BC*Ho*Wo) return;
  int xo = idx % Wo; int yo = (idx / Wo) % Ho; int c = idx / (Wo*Ho);
  const float* p = in + ((size_t)c*H + 2*yo)*W + 2*xo;
  out[idx] = fmaxf(fmaxf(p[0],p[1]), fmaxf(p[W],p[W+1]));
}

// ---------------- Mamba (fp32) ----------------
__global__ void k_build_tok(const float* __restrict__ p4, const float* __restrict__ cls,
                            float* __restrict__ hidden, float* __restrict__ residual){
  int idx = blockIdx.x*blockDim.x+threadIdx.x;
  if (idx >= 2*65*512) return;
  int d = idx % 512; int l = (idx/512)%65; int b = idx/(512*65);
  float v = (l==0) ? cls[d] : p4[((size_t)b*512+d)*64 + (l-1)];
  hidden[idx]=v; residual[idx]=v;
}

__global__ void k_add_ln(float* __restrict__ residual, const float* __restrict__ hidden,
                         const float* __restrict__ nw, const float* __restrict__ nb, float* __restrict__ hs){
  int row = blockIdx.x;
  int t = threadIdx.x;
  __shared__ float red[256];
  size_t base = (size_t)row*512;
  float v0 = residual[base + t]       + hidden[base + t];
  float v1 = residual[base + 256 + t] + hidden[base + 256 + t];
  residual[base+t]=v0; residual[base+256+t]=v1;
  red[t]=v0+v1; __syncthreads();
  for(int o=128;o>0;o>>=1){ if(t<o) red[t]+=red[t+o]; __syncthreads(); }
  float mean = red[0]/512.f; __syncthreads();
  float d0=v0-mean, d1=v1-mean;
  red[t]=d0*d0+d1*d1; __syncthreads();
  for(int o=128;o>0;o>>=1){ if(t<o) red[t]+=red[t+o]; __syncthreads(); }
  float rstd = rsqrtf(red[0]/512.f + 1e-5f);
  hs[base+t]     = d0*rstd*nw[t]     + nb[t];
  hs[base+256+t] = d1*rstd*nw[256+t] + nb[256+t];
}

#define GBM 32
#define GBN 32
#define GBK 32
__global__ void k_gemm(const float* __restrict__ A, int lda, const float* __restrict__ Bw,
                       const float* __restrict__ bias, float* __restrict__ C,
                       int M, int N, int K, int act){
  __shared__ float As[GBM][GBK+1];
  __shared__ float Bs[GBN][GBK+1];
  int bm = blockIdx.y*GBM, bn = blockIdx.x*GBN;
  int t = threadIdx.x;
  float acc[4] = {0.f,0.f,0.f,0.f};
  int tm = t>>3, tn = (t&7)*4;
  for (int k0=0;k0<K;k0+=GBK) {
    for (int i=t; i<GBM*GBK; i+=256) {
      int m = i>>5, k = i&31;
      As[m][k] = (bm+m<M && k0+k<K)? A[(size_t)(bm+m)*lda + k0+k] : 0.f;
    }
    for (int i=t;i<GBN*GBK;i+=256){
      int n=i>>5,k=i&31;
      Bs[n][k] = (bn+n<N && k0+k<K)? Bw[(size_t)(bn+n)*K + k0+k] : 0.f;
    }
    __syncthreads();
    #pragma unroll
    for (int k=0;k<GBK;k++){
      float a = As[tm][k];
      acc[0]=fmaf(a,Bs[tn+0][k],acc[0]);
      acc[1]=fmaf(a,Bs[tn+1][k],acc[1]);
      acc[2]=fmaf(a,Bs[tn+2][k],acc[2]);
      acc[3]=fmaf(a,Bs[tn+3][k],acc[3]);
    }
    __syncthreads();
  }
  int m = bm+tm;
  if (m<M){
    #pragma unroll
    for (int j=0;j<4;j++){
      int n = bn+tn+j;
      if(n<N){
        float v = acc[j] + (bias? bias[n]:0.f);
        if (act==1) v = softplusf(v);
        C[(size_t)m*N + n] = v;
      }
    }
  }
}

__global__ void k_conv1d_silu(const float* __restrict__ xz, const float* __restrict__ cw,
                              const float* __restrict__ cb, float* __restrict__ xc){
  int d = blockIdx.x*blockDim.x + threadIdx.x;
  int l = blockIdx.y, b = blockIdx.z;
  if (d>=1024) return;
  float acc = cb[d];
  #pragma unroll
  for(int k=0;k<4;k++){
    int lp = l-3+k;
    if (lp>=0) acc = fmaf(xz[((size_t)(b*65+lp))*2048 + d], cw[d*4+k], acc);
  }
  xc[((size_t)(b*65+l))*1024 + d] = siluf(acc);
}

__global__ void k_scan(const float* __restrict__ dt, const float* __restrict__ xc,
                       const float* __restrict__ xdbl, const float* __restrict__ xz,
                       const float* __restrict__ Alog, const float* __restrict__ Dp,
                       float* __restrict__ gated){
  int gid = blockIdx.x*blockDim.x + threadIdx.x;
  if (gid >= 2*1024*16) return;
  int n = gid & 15;
  int d = (gid >> 4) & 1023;
  int b = gid >> 14;
  float A = -expf(Alog[d*16+n]);
  float Dv = Dp[d];
  float h = 0.f;
  for (int l=0;l<65;l++){
    size_t r = (size_t)(b*65+l);
    float dtv = dt[r*1024+d];
    float xcv = xc[r*1024+d];
    float Bn = xdbl[r*64 + 32 + n];
    float Cn = xdbl[r*64 + 48 + n];
    h = fmaf(expf(dtv*A), h, dtv*xcv*Bn);
    float y = h*Cn;
    y += __shfl_xor(y, 1); y += __shfl_xor(y, 2);
    y += __shfl_xor(y, 4); y += __shfl_xor(y, 8);
    if (n==0){
      float zv = xz[r*2048 + 1024 + d];
      gated[r*1024+d] = (y + Dv*xcv) * siluf(zv);
    }
  }
}

__global__ void k_xsp(const float* __restrict__ hidden, float* __restrict__ xsp){
  int idx = blockIdx.x*blockDim.x+threadIdx.x;
  if (idx>=2*512*64) return;
  int j = idx & 63; int c = (idx>>6)&511; int b = idx>>15;
  xsp[idx] = hidden[((size_t)(b*65 + 1 + j))*512 + c];
}

__global__ void k_conv1x1(const float* __restrict__ in, const float* __restrict__ w,
                          const float* __restrict__ bias, float* __restrict__ out){
  int hw = blockIdx.x*blockDim.x+threadIdx.x; if (hw>=128*128) return;
  int o = blockIdx.y, b = blockIdx.z;
  float acc = bias[o];
  #pragma unroll
  for(int c=0;c<32;c++) acc = fmaf(in[((size_t)(b*32+c))*16384 + hw], w[o*32+c], acc);
  out[((size_t)(b*4+o))*16384 + hw] = acc;
}

__global__ void k_resize16(const float* __restrict__ in, float* __restrict__ out){
  size_t idx = (size_t)blockIdx.x*blockDim.x + threadIdx.x;
  if (idx >= (size_t)2*4*2048*2048) return;
  int x = idx & 2047; int y = (int)((idx>>11)&2047); int c = (int)(idx>>22);
  float sx = ((float)x+0.5f)*(1.f/16.f) - 0.5f;
  float sy = ((float)y+0.5f)*(1.f/16.f) - 0.5f;
  int x0 = (int)floorf(sx); float fx = sx-(float)x0;
  int y0 = (int)floorf(sy); float fy = sy-(float)y0;
  int x0c = max(x0,0), x1c = min(x0+1,127);
  int y0c = max(y0,0), y1c = min(y0+1,127);
  const float* p = in + (size_t)c*16384;
  float v00=p[y0c*128+x0c], v01=p[y0c*128+x1c], v10=p[y1c*128+x0c], v11=p[y1c*128+x1c];
  out[idx] = (1.f-fy)*((1.f-fx)*v00 + fx*v01) + fy*((1.f-fx)*v10 + fx*v11);
}

// ---------------- host ----------------
static inline void gemm_launch(hipStream_t s, const float* A, int lda, const float* Bw,
                               const float* bias, float* C, int M, int N, int K, int act){
  dim3 grid((N+GBN-1)/GBN, (M+GBM-1)/GBM);
  hipLaunchKernelGGL(k_gemm, grid, dim3(256), 0, s, A, lda, Bw, bias, C, M, N, K, act);
}

#define MAX_A_ELEMS (16384*576)
#define MAX_B_ELEMS (512*4608)

extern "C" void kernel_launch(void* const* d_in, const int* in_sizes, int n_in,
                              void* d_out, int out_size, void* d_ws, size_t ws_size,
                              hipStream_t stream) {
  const float* x        = (const float*)d_in[0];
  const float* masks    = (const float*)d_in[1];
  const float* ew1[4] = {(const float*)d_in[2],(const float*)d_in[6],(const float*)d_in[10],(const float*)d_in[14]};
  const float* eb1[4] = {(const float*)d_in[3],(const float*)d_in[7],(const float*)d_in[11],(const float*)d_in[15]};
  const float* ew2[4] = {(const float*)d_in[4],(const float*)d_in[8],(const float*)d_in[12],(const float*)d_in[16]};
  const float* eb2[4] = {(const float*)d_in[5],(const float*)d_in[9],(const float*)d_in[13],(const float*)d_in[17]};
  const float* cls      = (const float*)d_in[18];
  const float* norm_w   = (const float*)d_in[19];
  const float* norm_b   = (const float*)d_in[20];
  const float* in_proj  = (const float*)d_in[21];
  const float* conv1d_w = (const float*)d_in[22];
  const float* conv1d_b = (const float*)d_in[23];
  const float* x_proj   = (const float*)d_in[24];
  const float* dt_w     = (const float*)d_in[25];
  const float* dt_b     = (const float*)d_in[26];
  const float* A_log    = (const float*)d_in[27];
  const float* D_ssm    = (const float*)d_in[28];
  const float* out_proj = (const float*)d_in[29];
  const float* dup_w[4] = {(const float*)d_in[30],(const float*)d_in[36],(const float*)d_in[42],(const float*)d_in[48]};
  const float* dup_b[4] = {(const float*)d_in[31],(const float*)d_in[37],(const float*)d_in[43],(const float*)d_in[49]};
  const float* dw1[4]   = {(const float*)d_in[32],(const float*)d_in[38],(const float*)d_in[44],(const float*)d_in[50]};
  const float* db1[4]   = {(const float*)d_in[33],(const float*)d_in[39],(const float*)d_in[45],(const float*)d_in[51]};
  const float* dw2[4]   = {(const float*)d_in[34],(const float*)d_in[40],(const float*)d_in[46],(const float*)d_in[52]};
  const float* db2[4]   = {(const float*)d_in[35],(const float*)d_in[41],(const float*)d_in[47],(const float*)d_in[53]};
  const float* final_w  = (const float*)d_in[54];
  const float* final_b  = (const float*)d_in[55];
  float* out = (float*)d_out;

  float* W = (float*)d_ws;
  size_t off = 0;
  auto alloc = [&](size_t n){ float* p = W + off; off += n; return p; };

  float* Tre = alloc(32768);  float* Tim = alloc(32768);
  float* Fre = alloc(32768);  float* Fim = alloc(32768);
  float* Gre = alloc(196608); float* Gim = alloc(196608);
  float* xfreq = alloc(98304);
  float* tmpA = alloc(2097152);
  float* e1 = alloc(2097152);
  float* p1 = alloc(524288);
  float* e2 = alloc(1048576);
  float* p2 = alloc(262144);
  float* e3 = alloc(524288);
  float* p3 = alloc(131072);
  float* e4 = alloc(262144);
  float* p4 = alloc(65536);
  float* hidden   = alloc(66560);
  float* residual = alloc(66560);
  float* hs  = alloc(66560);
  float* xz  = alloc(266240);
  float* xc  = alloc(133120);
  float* xdbl= alloc(8320);
  float* dtb = alloc(133120);
  float* gated = alloc(133120);
  float* xsp = alloc(65536);
  float* tmpB = alloc(1048576);
  float* d4 = alloc(131072);
  float* d3 = alloc(262144);
  float* d2 = alloc(524288);
  float* d1 = alloc(1048576);
  float* fin = alloc(131072);
  (void)ws_size; (void)n_in; (void)in_sizes; (void)out_size;

  // hi/lo GEMM operand planes live in d_out (134MB, fully rewritten by k_resize16 at the end)
  f16* Ahi = (f16*)d_out;
  f16* Alo = Ahi + MAX_A_ELEMS;
  f16* Bhi = Alo + MAX_A_ELEMS;
  f16* Blo = Bhi + MAX_B_ELEMS;

  // ---- frequency band split ----
  hipLaunchKernelGGL(k_dft_rows, dim3(128,2), dim3(128), 0, stream, x, Tre, Tim);
  hipLaunchKernelGGL(k_dft_cols, dim3(128,2), dim3(128), 0, stream, Tre, Tim, Fre, Fim);
  hipLaunchKernelGGL(k_idft_cols, dim3(128,3,2), dim3(128), 0, stream, Fre, Fim, masks, Gre, Gim);
  hipLaunchKernelGGL(k_idft_rows, dim3(128,3,2), dim3(128), 0, stream, Gre, Gim, xfreq);

  // ---- MFMA conv via im2col (split f16) ----
  auto ctz = [](int v){ int s=0; while(!(v&1)){v>>=1;s++;} return s; };
  auto conv_bf = [&](const float* i1,int C1,const float* i2,int C2,
                     const float* w,const float* bias, float* o,
                     int Co,int H,int Wd,int relu){
    int Ci=C1+C2, K=Ci*9, Kp=(K+31)&~31, Np=(Co+63)&~63;
    int M=2*H*Wd;
    int wsh=ctz(Wd), hwsh=ctz(H*Wd);
    hipLaunchKernelGGL(k_w2hl, dim3((Kp+255)/256, Np), dim3(256), 0, stream, w, Bhi, Blo, Co, K, Kp);
    int maxRows = (MAX_A_ELEMS / Kp) & ~63;
    for (int m0=0; m0<M; m0+=maxRows){
      int mc = M-m0 < maxRows ? M-m0 : maxRows;
      hipLaunchKernelGGL(k_im2col, dim3((Kp+255)/256, mc), dim3(256), 0, stream,
                         i1, C1, i2, C2, H, Wd, wsh, hwsh, K, Kp, m0, 1, Ahi, Alo);
      hipLaunchKernelGGL(k_gemm_hl, dim3(mc/64, Np/64), dim3(256), 0, stream,
                         Bhi, Blo, Ahi, Alo, bias, o, Co, Kp, m0, wsh, hwsh, Co, relu, 0);
    }
  };
  auto up_bf = [&](const float* in,const float* w,const float* bias,float* o,
                   int Ci,int Co,int Hi){
    int K=Ci, Kp=Ci, N=4*Co, Np=N;
    int M=2*Hi*Hi;
    int wsh=ctz(Hi), hwsh=ctz(Hi*Hi);
    hipLaunchKernelGGL(k_upw2hl, dim3((Kp+255)/256, Np), dim3(256), 0, stream, w, Bhi, Blo, Co, K, Kp);
    hipLaunchKernelGGL(k_im2col, dim3((Kp+255)/256, M), dim3(256), 0, stream,
                       in, Ci, (const float*)nullptr, 0, Hi, Hi, wsh, hwsh, K, Kp, 0, 0, Ahi, Alo);
    hipLaunchKernelGGL(k_gemm_hl, dim3(M/64, Np/64), dim3(256), 0, stream,
                       Bhi, Blo, Ahi, Alo, bias, o, N, Kp, 0, wsh, hwsh, Co, 0, 1);
  };

  // ---- encoder ----
  conv_bf(xfreq,3,  nullptr,0, ew1[0], eb1[0], tmpA, 64, 128,128, 1);
  conv_bf(tmpA,64,  nullptr,0, ew2[0], eb2[0], e1,   64, 128,128, 1);
  hipLaunchKernelGGL(k_maxpool2, dim3((2*64*64*64+255)/256), dim3(256), 0, stream, e1, p1, 2*64, 128,128);
  conv_bf(p1,64,    nullptr,0, ew1[1], eb1[1], tmpA, 128, 64,64, 1);
  conv_bf(tmpA,128, nullptr,0, ew2[1], eb2[1], e2,   128, 64,64, 1);
  hipLaunchKernelGGL(k_maxpool2, dim3((2*128*32*32+255)/256), dim3(256), 0, stream, e2, p2, 2*128, 64,64);
  conv_bf(p2,128,   nullptr,0, ew1[2], eb1[2], tmpA, 256, 32,32, 1);
  conv_bf(tmpA,256, nullptr,0, ew2[2], eb2[2], e3,   256, 32,32, 1);
  hipLaunchKernelGGL(k_maxpool2, dim3((2*256*16*16+255)/256), dim3(256), 0, stream, e3, p3, 2*256, 32,32);
  conv_bf(p3,256,   nullptr,0, ew1[3], eb1[3], tmpA, 512, 16,16, 1);
  conv_bf(tmpA,512, nullptr,0, ew2[3], eb2[3], e4,   512, 16,16, 1);
  hipLaunchKernelGGL(k_maxpool2, dim3((2*512*8*8+255)/256), dim3(256), 0, stream, e4, p4, 2*512, 16,16);

  // ---- mamba stack (fp32) ----
  hipLaunchKernelGGL(k_build_tok, dim3((2*65*512+255)/256), dim3(256), 0, stream, p4, cls, hidden, residual);
  for (int l=0;l<24;l++){
    const float* nw   = norm_w   + (size_t)l*512;
    const float* nb   = norm_b   + (size_t)l*512;
    const float* inW  = in_proj  + (size_t)l*2048*512;
    const float* cw   = conv1d_w + (size_t)l*1024*4;
    const float* cb   = conv1d_b + (size_t)l*1024;
    const float* xpW  = x_proj   + (size_t)l*64*1024;
    const float* dtW  = dt_w     + (size_t)l*1024*32;
    const float* dtB  = dt_b     + (size_t)l*1024;
    const float* Alg  = A_log    + (size_t)l*1024*16;
    const float* Dp   = D_ssm    + (size_t)l*1024;
    const float* outW = out_proj + (size_t)l*512*1024;

    hipLaunchKernelGGL(k_add_ln, dim3(130), dim3(256), 0, stream, residual, hidden, nw, nb, hs);
    gemm_launch(stream, hs, 512, inW, nullptr, xz, 130, 2048, 512, 0);
    hipLaunchKernelGGL(k_conv1d_silu, dim3(4,65,2), dim3(256), 0, stream, xz, cw, cb, xc);
    gemm_launch(stream, xc, 1024, xpW, nullptr, xdbl, 130, 64, 1024, 0);
    gemm_launch(stream, xdbl, 64, dtW, dtB, dtb, 130, 1024, 32, 1);
    hipLaunchKernelGGL(k_scan, dim3(128), dim3(256), 0, stream, dtb, xc, xdbl, xz, Alg, Dp, gated);
    gemm_launch(stream, gated, 1024, outW, nullptr, hidden, 130, 512, 1024, 0);
  }
  hipLaunchKernelGGL(k_xsp, dim3((2*512*64+255)/256), dim3(256), 0, stream, hidden, xsp);

  // ---- decoder ----
  up_bf(xsp, dup_w[0], dup_b[0], tmpB, 512, 256, 8);
  conv_bf(e4,512, tmpB,256, dw1[0], db1[0], tmpA, 256, 16,16, 1);
  conv_bf(tmpA,256, nullptr,0, dw2[0], db2[0], d4, 256, 16,16, 1);
  up_bf(d4, dup_w[1], dup_b[1], tmpB, 256, 128, 16);
  conv_bf(e3,256, tmpB,128, dw1[1], db1[1], tmpA, 128, 32,32, 1);
  conv_bf(tmpA,128, nullptr,0, dw2[1], db2[1], d3, 128, 32,32, 1);
  up_bf(d3, dup_w[2], dup_b[2], tmpB, 128, 64, 32);
  conv_bf(e2,128, tmpB,64, dw1[2], db1[2], tmpA, 64, 64,64, 1);
  conv_bf(tmpA,64, nullptr,0, dw2[2], db2[2], d2, 64, 64,64, 1);
  up_bf(d2, dup_w[3], dup_b[3], tmpB, 64, 32, 64);
  conv_bf(e1,64, tmpB,32, dw1[3], db1[3], tmpA, 32, 128,128, 1);
  conv_bf(tmpA,32, nullptr,0, dw2[3], db2[3], d1, 32, 128,128, 1);

  // ---- head ----
  hipLaunchKernelGGL(k_conv1x1, dim3((16384+255)/256, 4, 2), dim3(256), 0, stream, d1, final_w, final_b, fin);
  hipLaunchKernelGGL(k_resize16, dim3((size_t)(2*4*2048*2048)/256), dim3(256), 0, stream, fin, out);
}

// Round 5
// 3871.201 us; speedup vs baseline: 3.6247x; 2.4965x over previous
//
#include <hip/hip_runtime.h>
#include <math.h>

#define PI_F 3.14159265358979323846f
typedef _Float16 f16;
typedef __attribute__((ext_vector_type(8))) _Float16 f16x8;
typedef __attribute__((ext_vector_type(4))) float f32x4;

__device__ __forceinline__ float siluf(float x){ return x / (1.f + expf(-x)); }
__device__ __forceinline__ float softplusf(float x){ return fmaxf(x,0.f) + log1pf(expf(-fabsf(x))); }
__device__ __forceinline__ void f2hl(float v, f16& hi, f16& lo){
  hi = (f16)v;
  lo = (f16)(v - (float)hi);
}

// ---------------- DFT band filtering ----------------
__global__ void k_dft_rows(const float* __restrict__ x, float* __restrict__ Tre, float* __restrict__ Tim){
  int v = threadIdx.x; int y = blockIdx.x; int b = blockIdx.y;
  __shared__ float cs[128], sn[128];
  float ang = -2.f*PI_F*(float)v/128.f;
  cs[v]=cosf(ang); sn[v]=sinf(ang);
  __syncthreads();
  const float* row = x + (b*128+y)*128;
  float re=0.f, im=0.f;
  for(int n=0;n<128;n++){ float xv=row[n]; int ph=(v*n)&127; re=fmaf(xv,cs[ph],re); im=fmaf(xv,sn[ph],im); }
  int o=(b*128+y)*128+v; Tre[o]=re; Tim[o]=im;
}
__global__ void k_dft_cols(const float* __restrict__ Tre, const float* __restrict__ Tim,
                           float* __restrict__ Fre, float* __restrict__ Fim){
  int v=threadIdx.x; int u=blockIdx.x; int b=blockIdx.y;
  __shared__ float cs[128], sn[128];
  float ang=-2.f*PI_F*(float)v/128.f; cs[v]=cosf(ang); sn[v]=sinf(ang);
  __syncthreads();
  float re=0.f,im=0.f;
  for(int y=0;y<128;y++){
    int ph=(u*y)&127; float c=cs[ph], s=sn[ph];
    int o=(b*128+y)*128+v;
    float tr=Tre[o], ti=Tim[o];
    re += tr*c - ti*s; im += tr*s + ti*c;
  }
  int o=(b*128+u)*128+v; Fre[o]=re; Fim[o]=im;
}
__global__ void k_idft_cols(const float* __restrict__ Fre,const float* __restrict__ Fim,
                            const float* __restrict__ mask, float* __restrict__ Gre,float* __restrict__ Gim){
  int v=threadIdx.x; int y=blockIdx.x; int m=blockIdx.y; int b=blockIdx.z;
  __shared__ float cs[128], sn[128];
  float ang=-2.f*PI_F*(float)v/128.f; cs[v]=cosf(ang); sn[v]=sinf(ang);
  __syncthreads();
  float re=0.f,im=0.f;
  for(int u=0;u<128;u++){
    int ph=(u*y)&127; float c=cs[ph], s=sn[ph];
    float w = mask[(m*128+u)*128+v];
    int o=(b*128+u)*128+v;
    float fr=Fre[o]*w, fi=Fim[o]*w;
    re += fr*c + fi*s;
    im += fi*c - fr*s;
  }
  int o=((b*3+m)*128+y)*128+v;
  Gre[o]=re*(1.f/128.f); Gim[o]=im*(1.f/128.f);
}
__global__ void k_idft_rows(const float* __restrict__ Gre,const float* __restrict__ Gim, float* __restrict__ xf){
  int xc=threadIdx.x; int y=blockIdx.x; int m=blockIdx.y; int b=blockIdx.z;
  __shared__ float cs[128], sn[128];
  float ang=-2.f*PI_F*(float)xc/128.f; cs[xc]=cosf(ang); sn[xc]=sinf(ang);
  __syncthreads();
  float re=0.f;
  const float* gr=Gre+((b*3+m)*128+y)*128;
  const float* gi=Gim+((b*3+m)*128+y)*128;
  for(int v=0;v<128;v++){
    int ph=(v*xc)&127;
    re += gr[v]*cs[ph] + gi[v]*sn[ph];
  }
  xf[((b*3+m)*128+y)*128+xc] = re*(1.f/128.f);
}

// ---------------- f16 hi/lo prep kernels ----------------
__global__ void k_w2hl(const float* __restrict__ w, f16* __restrict__ dh, f16* __restrict__ dl,
                       int N, int K, int Kp){
  int k = blockIdx.x*256 + threadIdx.x;
  int n = blockIdx.y;
  if (k >= Kp) return;
  float v = (n < N && k < K) ? w[(size_t)n*K + k] : 0.f;
  f16 h,l; f2hl(v,h,l);
  dh[(size_t)n*Kp + k] = h; dl[(size_t)n*Kp + k] = l;
}
__global__ void k_upw2hl(const float* __restrict__ w, f16* __restrict__ dh, f16* __restrict__ dl,
                         int Co, int K, int Kp){
  int k = blockIdx.x*256 + threadIdx.x;
  int n = blockIdx.y;
  if (k >= Kp) return;
  int o = n>>2, p=(n>>1)&1, q=n&1;
  float v = (k < K) ? w[(((size_t)k*Co + o)*2 + p)*2 + q] : 0.f;
  f16 h,l; f2hl(v,h,l);
  dh[(size_t)n*Kp + k] = h; dl[(size_t)n*Kp + k] = l;
}

// im2col: rows m0..m0+mc of M=B*H*W. k = ci*9 + (ky*3+kx) (ks3) or ci (ks1).
__global__ void k_im2col(const float* __restrict__ in1, int C1, const float* __restrict__ in2, int C2,
                         int H, int W, int wsh, int hwsh, int K, int Kp, int m0, int ks3,
                         f16* __restrict__ Ah, f16* __restrict__ Al){
  int k = blockIdx.x*256 + threadIdx.x;
  int lm = blockIdx.y;
  if (k >= Kp) return;
  float val = 0.f;
  if (k < K){
    int ci, dy, dx;
    if (ks3){ ci = k/9; int tt = k - ci*9; int r3 = tt/3; dy = r3 - 1; dx = tt - r3*3 - 1; }
    else { ci = k; dy = 0; dx = 0; }
    int m = m0 + lm;
    int b = m >> hwsh;
    int hw = m & ((1<<hwsh)-1);
    int y = (hw >> wsh) + dy;
    int x = (hw & (W-1)) + dx;
    if (y >= 0 && y < H && x >= 0 && x < W){
      val = (ci < C1) ? in1[(((size_t)b*C1 + ci)*H + y)*W + x]
                      : in2[(((size_t)b*C2 + (ci-C1))*H + y)*W + x];
    }
  }
  f16 h,l; f2hl(val,h,l);
  Ah[(size_t)lm*Kp + k] = h; Al[(size_t)lm*Kp + k] = l;
}

// mamba weight convert: 4 tensors per layer -> hi/lo planes (dt K padded 32->64)
__global__ void k_wcvt4(const float* __restrict__ wi, const float* __restrict__ wx,
                        const float* __restrict__ wdt, const float* __restrict__ wo,
                        f16* __restrict__ wih, f16* __restrict__ wil,
                        f16* __restrict__ wxh, f16* __restrict__ wxl,
                        f16* __restrict__ wdh, f16* __restrict__ wdl,
                        f16* __restrict__ woh, f16* __restrict__ wol){
  int i = blockIdx.x*256 + threadIdx.x;
  f16 h,l;
  if (i < 1048576){
    f2hl(wi[i],h,l); wih[i]=h; wil[i]=l;
  } else if (i < 1114112){
    int j = i - 1048576; f2hl(wx[j],h,l); wxh[j]=h; wxl[j]=l;
  } else if (i < 1179648){
    int j = i - 1114112; int n=j>>6, k=j&63;
    float v = (k<32) ? wdt[n*32+k] : 0.f;
    f2hl(v,h,l); wdh[j]=h; wdl[j]=l;
  } else if (i < 1703936){
    int j = i - 1179648; f2hl(wo[j],h,l); woh[j]=h; wol[j]=l;
  }
}

// zero pad rows 130..191 of mamba activation hi/lo planes
__global__ void k_zero_pads(f16* hsh, f16* hsl, f16* xch, f16* xcl,
                            f16* xdh, f16* xdl, f16* gth, f16* gtl){
  int i = blockIdx.x*256 + threadIdx.x;
  if (i >= 62*2624) return;
  int r = 130 + i/2624, c = i%2624;
  if (c < 512){ hsh[r*512+c]=(f16)0.f; hsl[r*512+c]=(f16)0.f; }
  else if (c < 1536){ int k=c-512; xch[r*1024+k]=(f16)0.f; xcl[r*1024+k]=(f16)0.f; }
  else if (c < 1600){ int k=c-1536; xdh[r*64+k]=(f16)0.f; xdl[r*64+k]=(f16)0.f; }
  else { int k=c-1600; gth[r*1024+k]=(f16)0.f; gtl[r*1024+k]=(f16)0.f; }
}

// ---------------- pipelined split-f16 MFMA GEMM ----------------
// out = W(Np,Kp) x P(Mp,Kp)^T, hi/lo f16 planes, 3 MFMAs per fragment pair.
// 3-deep LDS pipeline: global_load_lds staging, raw s_barrier, counted vmcnt.
// mode 0: conv NCHW out[(b*Co+co)*HW+hw], bias[co], act. (m = m0+pm)
// mode 1: up2 scatter co->(o,p,q), m->(b,i,j), bias[o]
// mode 2: plain out[m*ldc+co] (m<Mreal), bias[co] optional, act; optional hi/lo emit
// act: 0 none, 1 softplus, 2 relu
#define GLLDS(gp, ls) __builtin_amdgcn_global_load_lds( \
    (const __attribute__((address_space(1))) void*)(gp), \
    (__attribute__((address_space(3))) void*)(ls), 16, 0, 0)

__global__ __launch_bounds__(256) void k_gemm_hl(
    const f16* __restrict__ Wh, const f16* __restrict__ Wl,
    const f16* __restrict__ Ph, const f16* __restrict__ Pl,
    const float* __restrict__ bias, float* __restrict__ out,
    int N, int Kp, int m0, int wsh, int hwsh, int Co, int act, int mode,
    int Mreal, int ldc, f16* __restrict__ ehi, f16* __restrict__ elo)
{
  __shared__ __align__(16) f16 sm[3*4*2048];   // 3 buffers x 4 planes x (64 rows x 32 k)
  int bn = blockIdx.y*64;   // W rows (out features)
  int bm = blockIdx.x*64;   // P rows (pixels/tokens)
  int t = threadIdx.x;
  int lane = t & 63, wv = t >> 6;
  int wr = wv >> 1, wc = wv & 1;

  // ---- pre-load bias (keeps vmcnt clean inside the loop) ----
  float bv[2][4];
  {
    int cb = bn + wr*32 + (lane>>4)*4;
    #pragma unroll
    for (int ri=0;ri<2;ri++)
      #pragma unroll
      for (int r=0;r<4;r++){
        int co = cb + ri*16 + r;
        int idx = (mode==1) ? (co>>2) : co;
        int lim = (mode==1) ? (N>>2) : N;
        if (idx >= lim) idx = lim-1;
        bv[ri][r] = bias ? bias[idx] : 0.f;
      }
  }
  asm volatile("s_waitcnt vmcnt(0)" ::: "memory");

  // ---- staging addresses ----
  int rr = lane >> 2;
  int cg = (lane & 3) ^ ((lane >> 3) & 3);       // source chunk swizzle
  size_t gW = (size_t)(bn + wv*16 + rr)*Kp + cg*8;
  size_t gP = (size_t)(bm + wv*16 + rr)*Kp + cg*8;
  int lb = wv*512;

  // ---- fragment read offsets (f16 units) ----
  int rA = lane & 15, c = lane >> 4;
  int RW = wr*32 + rA; int sW = (RW>>1)&3;
  int offW = RW*32 + 8*(c ^ sW);
  int RP = wc*32 + rA; int sP = (RP>>1)&3;
  int offP = RP*32 + 8*(c ^ sP);

  f32x4 zz = {0.f,0.f,0.f,0.f};
  f32x4 acc[2][2];
  acc[0][0]=zz; acc[0][1]=zz; acc[1][0]=zz; acc[1][1]=zz;

  auto stage = [&](int bfi, int kk){
    GLLDS(Wh + gW + kk, &sm[(bfi*4+0)*2048 + lb]);
    GLLDS(Wl + gW + kk, &sm[(bfi*4+1)*2048 + lb]);
    GLLDS(Ph + gP + kk, &sm[(bfi*4+2)*2048 + lb]);
    GLLDS(Pl + gP + kk, &sm[(bfi*4+3)*2048 + lb]);
  };

  int nt = Kp >> 5;
  stage(0, 0);
  stage(1, (nt>1)?32:0);
  stage(2, (nt>2)?64:0);

  for (int tt = 0; tt < nt; ++tt){
    asm volatile("s_waitcnt vmcnt(8)" ::: "memory");
    __builtin_amdgcn_s_barrier();
    asm volatile("" ::: "memory");
    int bfi = tt % 3;
    int base = bfi*8192;
    f16x8 w0h = *(const f16x8*)&sm[base + offW];
    f16x8 w1h = *(const f16x8*)&sm[base + offW + 512];
    f16x8 w0l = *(const f16x8*)&sm[base + 2048 + offW];
    f16x8 w1l = *(const f16x8*)&sm[base + 2048 + offW + 512];
    f16x8 p0h = *(const f16x8*)&sm[base + 4096 + offP];
    f16x8 p1h = *(const f16x8*)&sm[base + 4096 + offP + 512];
    f16x8 p0l = *(const f16x8*)&sm[base + 6144 + offP];
    f16x8 p1l = *(const f16x8*)&sm[base + 6144 + offP + 512];
    acc[0][0] = __builtin_amdgcn_mfma_f32_16x16x32_f16(w0h, p0h, acc[0][0], 0,0,0);
    acc[0][1] = __builtin_amdgcn_mfma_f32_16x16x32_f16(w0h, p1h, acc[0][1], 0,0,0);
    acc[1][0] = __builtin_amdgcn_mfma_f32_16x16x32_f16(w1h, p0h, acc[1][0], 0,0,0);
    acc[1][1] = __builtin_amdgcn_mfma_f32_16x16x32_f16(w1h, p1h, acc[1][1], 0,0,0);
    acc[0][0] = __builtin_amdgcn_mfma_f32_16x16x32_f16(w0h, p0l, acc[0][0], 0,0,0);
    acc[0][1] = __builtin_amdgcn_mfma_f32_16x16x32_f16(w0h, p1l, acc[0][1], 0,0,0);
    acc[1][0] = __builtin_amdgcn_mfma_f32_16x16x32_f16(w1h, p0l, acc[1][0], 0,0,0);
    acc[1][1] = __builtin_amdgcn_mfma_f32_16x16x32_f16(w1h, p1l, acc[1][1], 0,0,0);
    acc[0][0] = __builtin_amdgcn_mfma_f32_16x16x32_f16(w0l, p0h, acc[0][0], 0,0,0);
    acc[0][1] = __builtin_amdgcn_mfma_f32_16x16x32_f16(w0l, p1h, acc[0][1], 0,0,0);
    acc[1][0] = __builtin_amdgcn_mfma_f32_16x16x32_f16(w1l, p0h, acc[1][0], 0,0,0);
    acc[1][1] = __builtin_amdgcn_mfma_f32_16x16x32_f16(w1l, p1h, acc[1][1], 0,0,0);
    __builtin_amdgcn_s_barrier();
    asm volatile("" ::: "memory");
    int kn = (tt+3 < nt) ? (tt+3)*32 : 0;
    stage(bfi, kn);
  }

  int HW = 1<<hwsh;
  int Wi = 1<<wsh;
  int Hi = 1<<(hwsh-wsh);
  #pragma unroll
  for (int ri=0;ri<2;ri++)
  #pragma unroll
  for (int ci=0;ci<2;ci++)
  #pragma unroll
  for (int r=0;r<4;r++){
    int co = bn + wr*32 + ri*16 + (lane>>4)*4 + r;
    int pm = bm + wc*32 + ci*16 + (lane&15);
    if (co < N){
      float v = acc[ri][ci][r];
      int m = m0 + pm;
      if (mode == 0){
        v += bv[ri][r];
        if (act == 2) v = fmaxf(v, 0.f);
        int b = m >> hwsh;
        int hw = m & (HW-1);
        out[((size_t)b*Co + co)*HW + hw] = v;
      } else if (mode == 1){
        int o = co>>2, p=(co>>1)&1, q=co&1;
        v += bv[ri][r];
        int b = m >> hwsh;
        int ij = m & (HW-1);
        int i = ij >> wsh, j = ij & (Wi-1);
        out[(((size_t)b*Co + o)*(2*Hi) + 2*i+p)*(2*Wi) + 2*j+q] = v;
      } else {
        if (m < Mreal){
          v += bv[ri][r];
          if (act == 1) v = softplusf(v);
          else if (act == 2) v = fmaxf(v, 0.f);
          out[(size_t)m*ldc + co] = v;
          if (ehi){
            f16 h,l; f2hl(v,h,l);
            ehi[(size_t)m*ldc + co] = h;
            elo[(size_t)m*ldc + co] = l;
          }
        }
      }
    }
  }
}

__global__ void k_maxpool2(const float* __restrict__ in, float* __restrict__ out, int BC, int H, int W){
  int Ho=H/2, Wo=W/2;
  int idx = blockIdx.x*blockDim.x + threadIdx.x;
  if (idx >= BC*Ho*Wo) return;
  int xo = idx % Wo; int yo = (idx / Wo) % Ho; int c = idx / (Wo*Ho);
  const float* p = in + ((size_t)c*H + 2*yo)*W + 2*xo;
  out[idx] = fmaxf(fmaxf(p[0],p[1]), fmaxf(p[W],p[W+1]));
}

// ---------------- Mamba ----------------
__global__ void k_build_tok(const float* __restrict__ p4, const float* __restrict__ cls,
                            float* __restrict__ hidden, float* __restrict__ residual){
  int idx = blockIdx.x*blockDim.x+threadIdx.x;
  if (idx >= 2*65*512) return;
  int d = idx % 512; int l = (idx/512)%65; int b = idx/(512*65);
  float v = (l==0) ? cls[d] : p4[((size_t)b*512+d)*64 + (l-1)];
  hidden[idx]=v; residual[idx]=v;
}

// residual += hidden; hs_hl = LN(residual)*nw + nb  (hi/lo planes, 130 rows)
__global__ void k_add_ln(float* __restrict__ residual, const float* __restrict__ hidden,
                         const float* __restrict__ nw, const float* __restrict__ nb,
                         f16* __restrict__ hsh, f16* __restrict__ hsl){
  int row = blockIdx.x;
  int t = threadIdx.x;
  __shared__ float red[256];
  size_t base = (size_t)row*512;
  float v0 = residual[base + t]       + hidden[base + t];
  float v1 = residual[base + 256 + t] + hidden[base + 256 + t];
  residual[base+t]=v0; residual[base+256+t]=v1;
  red[t]=v0+v1; __syncthreads();
  for(int o=128;o>0;o>>=1){ if(t<o) red[t]+=red[t+o]; __syncthreads(); }
  float mean = red[0]/512.f; __syncthreads();
  float d0=v0-mean, d1=v1-mean;
  red[t]=d0*d0+d1*d1; __syncthreads();
  for(int o=128;o>0;o>>=1){ if(t<o) red[t]+=red[t+o]; __syncthreads(); }
  float rstd = rsqrtf(red[0]/512.f + 1e-5f);
  float a = d0*rstd*nw[t]     + nb[t];
  float b = d1*rstd*nw[256+t] + nb[256+t];
  f16 h,l;
  f2hl(a,h,l); hsh[base+t]=h;     hsl[base+t]=l;
  f2hl(b,h,l); hsh[base+256+t]=h; hsl[base+256+t]=l;
}

// depthwise causal conv1d (k=4) + bias + silu -> xc fp32 + hi/lo planes
__global__ void k_conv1d_silu(const float* __restrict__ xz, const float* __restrict__ cw,
                              const float* __restrict__ cb, float* __restrict__ xc,
                              f16* __restrict__ xch, f16* __restrict__ xcl){
  int d = blockIdx.x*blockDim.x + threadIdx.x;
  int l = blockIdx.y, b = blockIdx.z;
  if (d>=1024) return;
  float acc = cb[d];
  #pragma unroll
  for(int k=0;k<4;k++){
    int lp = l-3+k;
    if (lp>=0) acc = fmaf(xz[((size_t)(b*65+lp))*2048 + d], cw[d*4+k], acc);
  }
  float v = siluf(acc);
  size_t o = ((size_t)(b*65+l))*1024 + d;
  xc[o] = v;
  f16 h,ll; f2hl(v,h,ll); xch[o]=h; xcl[o]=ll;
}

// selective scan; lane per (b,d,n); shfl-reduce over n=16; emits gated hi/lo
__global__ void k_scan(const float* __restrict__ dt, const float* __restrict__ xc,
                       const float* __restrict__ xdbl, const float* __restrict__ xz,
                       const float* __restrict__ Alog, const float* __restrict__ Dp,
                       f16* __restrict__ gth, f16* __restrict__ gtl){
  int gid = blockIdx.x*blockDim.x + threadIdx.x;
  if (gid >= 2*1024*16) return;
  int n = gid & 15;
  int d = (gid >> 4) & 1023;
  int b = gid >> 14;
  float A = -expf(Alog[d*16+n]);
  float Dv = Dp[d];
  float h = 0.f;
  for (int l=0;l<65;l++){
    size_t r = (size_t)(b*65+l);
    float dtv = dt[r*1024+d];
    float xcv = xc[r*1024+d];
    float Bn = xdbl[r*64 + 32 + n];
    float Cn = xdbl[r*64 + 48 + n];
    h = fmaf(expf(dtv*A), h, dtv*xcv*Bn);
    float y = h*Cn;
    y += __shfl_xor(y, 1); y += __shfl_xor(y, 2);
    y += __shfl_xor(y, 4); y += __shfl_xor(y, 8);
    if (n==0){
      float zv = xz[r*2048 + 1024 + d];
      float g = (y + Dv*xcv) * siluf(zv);
      f16 hh,lo; f2hl(g,hh,lo);
      gth[r*1024+d]=hh; gtl[r*1024+d]=lo;
    }
  }
}

__global__ void k_xsp(const float* __restrict__ hidden, float* __restrict__ xsp){
  int idx = blockIdx.x*blockDim.x+threadIdx.x;
  if (idx>=2*512*64) return;
  int j = idx & 63; int c = (idx>>6)&511; int b = idx>>15;
  xsp[idx] = hidden[((size_t)(b*65 + 1 + j))*512 + c];
}

__global__ void k_conv1x1(const float* __restrict__ in, const float* __restrict__ w,
                          const float* __restrict__ bias, float* __restrict__ out){
  int hw = blockIdx.x*blockDim.x+threadIdx.x; if (hw>=128*128) return;
  int o = blockIdx.y, b = blockIdx.z;
  float acc = bias[o];
  #pragma unroll
  for(int c=0;c<32;c++) acc = fmaf(in[((size_t)(b*32+c))*16384 + hw], w[o*32+c], acc);
  out[((size_t)(b*4+o))*16384 + hw] = acc;
}

__global__ void k_resize16(const float* __restrict__ in, float* __restrict__ out){
  size_t idx = (size_t)blockIdx.x*blockDim.x + threadIdx.x;
  if (idx >= (size_t)2*4*2048*2048) return;
  int x = idx & 2047; int y = (int)((idx>>11)&2047); int c = (int)(idx>>22);
  float sx = ((float)x+0.5f)*(1.f/16.f) - 0.5f;
  float sy = ((float)y+0.5f)*(1.f/16.f) - 0.5f;
  int x0 = (int)floorf(sx); float fx = sx-(float)x0;
  int y0 = (int)floorf(sy); float fy = sy-(float)y0;
  int x0c = max(x0,0), x1c = min(x0+1,127);
  int y0c = max(y0,0), y1c = min(y0+1,127);
  const float* p = in + (size_t)c*16384;
  float v00=p[y0c*128+x0c], v01=p[y0c*128+x1c], v10=p[y1c*128+x0c], v11=p[y1c*128+x1c];
  out[idx] = (1.f-fy)*((1.f-fx)*v00 + fx*v01) + fy*((1.f-fx)*v10 + fx*v11);
}

// ---------------- host ----------------
#define MAX_A_ELEMS (16384*576)
#define MAX_B_ELEMS (512*4608)

extern "C" void kernel_launch(void* const* d_in, const int* in_sizes, int n_in,
                              void* d_out, int out_size, void* d_ws, size_t ws_size,
                              hipStream_t stream) {
  const float* x        = (const float*)d_in[0];
  const float* masks    = (const float*)d_in[1];
  const float* ew1[4] = {(const float*)d_in[2],(const float*)d_in[6],(const float*)d_in[10],(const float*)d_in[14]};
  const float* eb1[4] = {(const float*)d_in[3],(const float*)d_in[7],(const float*)d_in[11],(const float*)d_in[15]};
  const float* ew2[4] = {(const float*)d_in[4],(const float*)d_in[8],(const float*)d_in[12],(const float*)d_in[16]};
  const float* eb2[4] = {(const float*)d_in[5],(const float*)d_in[9],(const float*)d_in[13],(const float*)d_in[17]};
  const float* cls      = (const float*)d_in[18];
  const float* norm_w   = (const float*)d_in[19];
  const float* norm_b   = (const float*)d_in[20];
  const float* in_proj  = (const float*)d_in[21];
  const float* conv1d_w = (const float*)d_in[22];
  const float* conv1d_b = (const float*)d_in[23];
  const float* x_proj   = (const float*)d_in[24];
  const float* dt_w     = (const float*)d_in[25];
  const float* dt_b     = (const float*)d_in[26];
  const float* A_log    = (const float*)d_in[27];
  const float* D_ssm    = (const float*)d_in[28];
  const float* out_proj = (const float*)d_in[29];
  const float* dup_w[4] = {(const float*)d_in[30],(const float*)d_in[36],(const float*)d_in[42],(const float*)d_in[48]};
  const float* dup_b[4] = {(const float*)d_in[31],(const float*)d_in[37],(const float*)d_in[43],(const float*)d_in[49]};
  const float* dw1[4]   = {(const float*)d_in[32],(const float*)d_in[38],(const float*)d_in[44],(const float*)d_in[50]};
  const float* db1[4]   = {(const float*)d_in[33],(const float*)d_in[39],(const float*)d_in[45],(const float*)d_in[51]};
  const float* dw2[4]   = {(const float*)d_in[34],(const float*)d_in[40],(const float*)d_in[46],(const float*)d_in[52]};
  const float* db2[4]   = {(const float*)d_in[35],(const float*)d_in[41],(const float*)d_in[47],(const float*)d_in[53]};
  const float* final_w  = (const float*)d_in[54];
  const float* final_b  = (const float*)d_in[55];
  float* out = (float*)d_out;

  float* W = (float*)d_ws;
  size_t off = 0;
  auto alloc = [&](size_t n){ float* p = W + off; off += n; return p; };

  float* Tre = alloc(32768);  float* Tim = alloc(32768);
  float* Fre = alloc(32768);  float* Fim = alloc(32768);
  float* Gre = alloc(196608); float* Gim = alloc(196608);
  float* xfreq = alloc(98304);
  float* tmpA = alloc(2097152);
  float* e1 = alloc(2097152);
  float* p1 = alloc(524288);
  float* e2 = alloc(1048576);
  float* p2 = alloc(262144);
  float* e3 = alloc(524288);
  float* p3 = alloc(131072);
  float* e4 = alloc(262144);
  float* p4 = alloc(65536);
  float* hidden   = alloc(66560);
  float* residual = alloc(66560);
  float* xz  = alloc(266240);
  float* xc  = alloc(133120);
  float* xdbl= alloc(8320);
  float* dtb = alloc(133120);
  float* xsp = alloc(65536);
  float* tmpB = alloc(1048576);
  float* d4 = alloc(131072);
  float* d3 = alloc(262144);
  float* d2 = alloc(524288);
  float* d1 = alloc(1048576);
  float* fin = alloc(131072);
  (void)ws_size; (void)n_in; (void)in_sizes; (void)out_size;

  // scratch planes in d_out (fully overwritten by k_resize16 at the end)
  f16* q = (f16*)d_out;
  f16* Ahi = q; q += MAX_A_ELEMS;
  f16* Alo = q; q += MAX_A_ELEMS;
  f16* Bhi = q; q += MAX_B_ELEMS;
  f16* Blo = q; q += MAX_B_ELEMS;
  f16* wi_h = q; q += 1048576;  f16* wi_l = q; q += 1048576;
  f16* wx_h = q; q += 65536;    f16* wx_l = q; q += 65536;
  f16* wdt_h = q; q += 65536;   f16* wdt_l = q; q += 65536;
  f16* wo_h = q; q += 524288;   f16* wo_l = q; q += 524288;
  f16* hs_h = q; q += 98304;    f16* hs_l = q; q += 98304;    // 192x512
  f16* xc_h = q; q += 196608;   f16* xc_l = q; q += 196608;   // 192x1024
  f16* xd_h = q; q += 12288;    f16* xd_l = q; q += 12288;    // 192x64
  f16* gt_h = q; q += 196608;   f16* gt_l = q; q += 196608;   // 192x1024

  // ---- frequency band split ----
  hipLaunchKernelGGL(k_dft_rows, dim3(128,2), dim3(128), 0, stream, x, Tre, Tim);
  hipLaunchKernelGGL(k_dft_cols, dim3(128,2), dim3(128), 0, stream, Tre, Tim, Fre, Fim);
  hipLaunchKernelGGL(k_idft_cols, dim3(128,3,2), dim3(128), 0, stream, Fre, Fim, masks, Gre, Gim);
  hipLaunchKernelGGL(k_idft_rows, dim3(128,3,2), dim3(128), 0, stream, Gre, Gim, xfreq);

  // ---- conv via im2col + pipelined MFMA ----
  auto ctz = [](int v){ int s=0; while(!(v&1)){v>>=1;s++;} return s; };
  auto conv_bf = [&](const float* i1,int C1,const float* i2,int C2,
                     const float* w,const float* bias, float* o,
                     int Co,int H,int Wd){
    int Ci=C1+C2, K=Ci*9, Kp=(K+31)&~31, Np=(Co+63)&~63;
    int M=2*H*Wd;
    int wsh=ctz(Wd), hwsh=ctz(H*Wd);
    hipLaunchKernelGGL(k_w2hl, dim3((Kp+255)/256, Np), dim3(256), 0, stream, w, Bhi, Blo, Co, K, Kp);
    int maxRows = (MAX_A_ELEMS / Kp) & ~63;
    for (int m0=0; m0<M; m0+=maxRows){
      int mc = M-m0 < maxRows ? M-m0 : maxRows;
      hipLaunchKernelGGL(k_im2col, dim3((Kp+255)/256, mc), dim3(256), 0, stream,
                         i1, C1, i2, C2, H, Wd, wsh, hwsh, K, Kp, m0, 1, Ahi, Alo);
      hipLaunchKernelGGL(k_gemm_hl, dim3(mc/64, Np/64), dim3(256), 0, stream,
                         Bhi, Blo, Ahi, Alo, bias, o, Co, Kp, m0, wsh, hwsh, Co, 2, 0,
                         1<<30, 0, (f16*)nullptr, (f16*)nullptr);
    }
  };
  auto up_bf = [&](const float* in,const float* w,const float* bias,float* o,
                   int Ci,int Co,int Hi){
    int Kp=Ci, N=4*Co;
    int M=2*Hi*Hi;
    int wsh=ctz(Hi), hwsh=ctz(Hi*Hi);
    hipLaunchKernelGGL(k_upw2hl, dim3((Kp+255)/256, N), dim3(256), 0, stream, w, Bhi, Blo, Co, Ci, Kp);
    hipLaunchKernelGGL(k_im2col, dim3((Kp+255)/256, M), dim3(256), 0, stream,
                       in, Ci, (const float*)nullptr, 0, Hi, Hi, wsh, hwsh, Ci, Kp, 0, 0, Ahi, Alo);
    hipLaunchKernelGGL(k_gemm_hl, dim3(M/64, N/64), dim3(256), 0, stream,
                       Bhi, Blo, Ahi, Alo, bias, o, N, Kp, 0, wsh, hwsh, Co, 0, 1,
                       1<<30, 0, (f16*)nullptr, (f16*)nullptr);
  };

  // ---- encoder ----
  conv_bf(xfreq,3,  nullptr,0, ew1[0], eb1[0], tmpA, 64, 128,128);
  conv_bf(tmpA,64,  nullptr,0, ew2[0], eb2[0], e1,   64, 128,128);
  hipLaunchKernelGGL(k_maxpool2, dim3((2*64*64*64+255)/256), dim3(256), 0, stream, e1, p1, 2*64, 128,128);
  conv_bf(p1,64,    nullptr,0, ew1[1], eb1[1], tmpA, 128, 64,64);
  conv_bf(tmpA,128, nullptr,0, ew2[1], eb2[1], e2,   128, 64,64);
  hipLaunchKernelGGL(k_maxpool2, dim3((2*128*32*32+255)/256), dim3(256), 0, stream, e2, p2, 2*128, 64,64);
  conv_bf(p2,128,   nullptr,0, ew1[2], eb1[2], tmpA, 256, 32,32);
  conv_bf(tmpA,256, nullptr,0, ew2[2], eb2[2], e3,   256, 32,32);
  hipLaunchKernelGGL(k_maxpool2, dim3((2*256*16*16+255)/256), dim3(256), 0, stream, e3, p3, 2*256, 32,32);
  conv_bf(p3,256,   nullptr,0, ew1[3], eb1[3], tmpA, 512, 16,16);
  conv_bf(tmpA,512, nullptr,0, ew2[3], eb2[3], e4,   512, 16,16);
  hipLaunchKernelGGL(k_maxpool2, dim3((2*512*8*8+255)/256), dim3(256), 0, stream, e4, p4, 2*512, 16,16);

  // ---- mamba stack (MFMA GEMMs) ----
  hipLaunchKernelGGL(k_build_tok, dim3((2*65*512+255)/256), dim3(256), 0, stream, p4, cls, hidden, residual);
  hipLaunchKernelGGL(k_zero_pads, dim3((62*2624+255)/256), dim3(256), 0, stream,
                     hs_h, hs_l, xc_h, xc_l, xd_h, xd_l, gt_h, gt_l);
  auto mgemm = [&](const f16* wh, const f16* wl, const f16* ph, const f16* pl,
                   const float* bias, float* o, int N, int Kp, int act,
                   f16* eh, f16* el){
    hipLaunchKernelGGL(k_gemm_hl, dim3(3, N/64), dim3(256), 0, stream,
                       wh, wl, ph, pl, bias, o, N, Kp, 0, 0, 0, 0, act, 2,
                       130, N, eh, el);
  };
  for (int l=0;l<24;l++){
    const float* nw   = norm_w   + (size_t)l*512;
    const float* nb   = norm_b   + (size_t)l*512;
    const float* inW  = in_proj  + (size_t)l*2048*512;
    const float* cw   = conv1d_w + (size_t)l*1024*4;
    const float* cb   = conv1d_b + (size_t)l*1024;
    const float* xpW  = x_proj   + (size_t)l*64*1024;
    const float* dtW  = dt_w     + (size_t)l*1024*32;
    const float* dtB  = dt_b     + (size_t)l*1024;
    const float* Alg  = A_log    + (size_t)l*1024*16;
    const float* Dp   = D_ssm    + (size_t)l*1024;
    const float* outW = out_proj + (size_t)l*512*1024;

    hipLaunchKernelGGL(k_wcvt4, dim3((1703936+255)/256), dim3(256), 0, stream,
                       inW, xpW, dtW, outW, wi_h, wi_l, wx_h, wx_l, wdt_h, wdt_l, wo_h, wo_l);
    hipLaunchKernelGGL(k_add_ln, dim3(130), dim3(256), 0, stream, residual, hidden, nw, nb, hs_h, hs_l);
    mgemm(wi_h, wi_l, hs_h, hs_l, nullptr, xz, 2048, 512, 0, nullptr, nullptr);
    hipLaunchKernelGGL(k_conv1d_silu, dim3(4,65,2), dim3(256), 0, stream, xz, cw, cb, xc, xc_h, xc_l);
    mgemm(wx_h, wx_l, xc_h, xc_l, nullptr, xdbl, 64, 1024, 0, xd_h, xd_l);
    mgemm(wdt_h, wdt_l, xd_h, xd_l, dtB, dtb, 1024, 64, 1, nullptr, nullptr);
    hipLaunchKernelGGL(k_scan, dim3(128), dim3(256), 0, stream, dtb, xc, xdbl, xz, Alg, Dp, gt_h, gt_l);
    mgemm(wo_h, wo_l, gt_h, gt_l, nullptr, hidden, 512, 1024, 0, nullptr, nullptr);
  }
  hipLaunchKernelGGL(k_xsp, dim3((2*512*64+255)/256), dim3(256), 0, stream, hidden, xsp);

  // ---- decoder ----
  up_bf(xsp, dup_w[0], dup_b[0], tmpB, 512, 256, 8);
  conv_bf(e4,512, tmpB,256, dw1[0], db1[0], tmpA, 256, 16,16);
  conv_bf(tmpA,256, nullptr,0, dw2[0], db2[0], d4, 256, 16,16);
  up_bf(d4, dup_w[1], dup_b[1], tmpB, 256, 128, 16);
  conv_bf(e3,256, tmpB,128, dw1[1], db1[1], tmpA, 128, 32,32);
  conv_bf(tmpA,128, nullptr,0, dw2[1], db2[1], d3, 128, 32,32);
  up_bf(d3, dup_w[2], dup_b[2], tmpB, 128, 64, 32);
  conv_bf(e2,128, tmpB,64, dw1[2], db1[2], tmpA, 64, 64,64);
  conv_bf(tmpA,64, nullptr,0, dw2[2], db2[2], d2, 64, 64,64);
  up_bf(d2, dup_w[3], dup_b[3], tmpB, 64, 32, 64);
  conv_bf(e1,64, tmpB,32, dw1[3], db1[3], tmpA, 32, 128,128);
  conv_bf(tmpA,32, nullptr,0, dw2[3], db2[3], d1, 32, 128,128);

  // ---- head ----
  hipLaunchKernelGGL(k_conv1x1, dim3((16384+255)/256, 4, 2), dim3(256), 0, stream, d1, final_w, final_b, fin);
  hipLaunchKernelGGL(k_resize16, dim3((size_t)(2*4*2048*2048)/256), dim3(256), 0, stream, fin, out);
}